// Round 1
// baseline (200.424 us; speedup 1.0000x reference)
//
#include <hip/hip_runtime.h>
#include <hip/hip_cooperative_groups.h>
#include <math.h>

namespace cg = cooperative_groups;

// ---------------------------------------------------------------------------
// FullGaussianProjector: B=1, N=512, 3 views, 224x224 out, half-res 112x112.
// R6: fuse all 3 launches into ONE cooperative kernel (2 grid syncs).
//   Theory: device work is ~25-35us; the ~60us remainder of the measured 90us
//   is per-dispatch overhead. One launch should recover most of it.
//   phase 1 (splat): 256 thr / 4 waves; 2 gaussians per thread in setup;
//                    tile cull/compact -> 4 waves x 1/4-list chunks, each lane
//                    owns a 2x2 px quad -> LDS float4 merge -> dm (ws).
//   phase 2 (blur):  2x (separable blur + where) in LDS; d2 kept in REGISTERS;
//                    per-block partials -> ws.
//   phase 3 (norm):  every block reduces 588 partials (double), writes
//                    (d2-mean)/(sd+eps) from registers. out written ONCE.
// Fallback: if hipLaunchCooperativeKernel fails, run the proven 3-kernel path.
// NOTE (R5 lesson): a,2b,c,op must stay f32 — bf16 on the exponent path
// fails absmax through the (wmax-wmin) normalization.
// ---------------------------------------------------------------------------

__device__ __forceinline__ float wave_min(float v) {
    #pragma unroll
    for (int o = 32; o >= 1; o >>= 1) v = fminf(v, __shfl_xor(v, o));
    return v;
}

struct SpS {  // splat phase
    float4 lsA[512];        // a, 2b, c, op
    float2 lsB[512];        // gx, gy
    float4 pS[3][64], pMn[3][64], pMx[3][64];  // cross-wave merge (waves 1..3)
    float red[4 * 6];       // cross-wave min/max scratch
    int cnt;
};
struct BlS {  // blur phase
    float A[28 * 29];
    float T[28 * 29];
    float r1[4], r2[4];
};
struct NmS {  // normalize phase
    double s1[256], s2[256];
};
union SmU { SpS sp; BlS bl; NmS nm; };  // max ~21.6 KB

__global__ __launch_bounds__(256, 3) void fused_all_kernel(
    const float* __restrict__ position, const float* __restrict__ cov3d,
    const float* __restrict__ opacity, const float* __restrict__ importance,
    float* __restrict__ dm, float2* __restrict__ partials,
    float* __restrict__ out) {
    __shared__ SmU sm;
    cg::grid_group gg = cg::this_grid();
    const int v = blockIdx.z;
    const int tx0 = blockIdx.x * 16, ty0 = blockIdx.y * 16;
    const int tid = threadIdx.x;
    const int lane = tid & 63, wave = tid >> 6;  // 4 waves

    // ================= phase 1: splat =================
    // setup: 2 gaussians per thread (n = tid, tid+256)
    float P0[3], P1[3], OP0, OP1;
    {
        const int n0 = tid, n1 = tid + 256;
        P0[0] = position[n0 * 3 + 0]; P0[1] = position[n0 * 3 + 1]; P0[2] = position[n0 * 3 + 2];
        P1[0] = position[n1 * 3 + 0]; P1[1] = position[n1 * 3 + 1]; P1[2] = position[n1 * 3 + 2];
        OP0 = opacity[n0] * fminf(fmaxf(importance[n0], 0.5f), 2.0f);
        OP1 = opacity[n1] * fminf(fmaxf(importance[n1], 0.5f), 2.0f);
    }
    if (tid == 0) sm.sp.cnt = 0;
    {
        float vals[6] = { fminf(P0[0], P1[0]), fminf(-P0[0], -P1[0]),
                          fminf(P0[1], P1[1]), fminf(-P0[1], -P1[1]),
                          fminf(P0[2], P1[2]), fminf(-P0[2], -P1[2]) };
        #pragma unroll
        for (int k = 0; k < 6; ++k) {
            float r = wave_min(vals[k]);
            if (lane == 0) sm.sp.red[wave * 6 + k] = r;
        }
    }
    __syncthreads();
    float mn6[6];
    #pragma unroll
    for (int k = 0; k < 6; ++k) {
        float r = sm.sp.red[k];
        #pragma unroll
        for (int w = 1; w < 4; ++w) r = fminf(r, sm.sp.red[w * 6 + k]);
        mn6[k] = r;
    }
    const float pmn[3] = {mn6[0], mn6[2], mn6[4]};
    const float pmx[3] = {-mn6[1], -mn6[3], -mn6[5]};
    int ix, iy;
    if (v == 0)      { ix = 0; iy = 1; }
    else if (v == 1) { ix = 0; iy = 2; }
    else             { ix = 2; iy = 1; }
    float mnx = pmn[ix], mxx = pmx[ix], mny = pmn[iy], mxy = pmx[iy];
    float rngx = mxx - mnx + 1e-6f;
    float mnx2 = mnx - 0.5f * rngx;
    float mxx2 = mxx + 0.5f * rngx;
    rngx = mxx2 - mnx2 + 1e-6f;
    float rngy = mxy - mny + 1e-6f;
    float mny2 = mny - 0.5f * rngy;
    float mxy2 = mxy + 0.5f * rngy;
    rngy = mxy2 - mny2 + 1e-6f;
    const float bx0 = (float)(tx0 >> 1), bx1 = (float)((tx0 + 15) >> 1);
    const float by0 = (float)(ty0 >> 1), by1 = (float)((ty0 + 15) >> 1);

    // cull + compact, 2 passes (math verbatim from verified 512-thr version)
    for (int g = 0; g < 2; ++g) {
        const int n = tid + (g << 8);
        const float p0 = g ? P1[0] : P0[0];
        const float p1 = g ? P1[1] : P0[1];
        const float p2 = g ? P1[2] : P0[2];
        const float opimp = g ? OP1 : OP0;
        float c00 = cov3d[n * 9 + 0], c01 = cov3d[n * 9 + 1], c02 = cov3d[n * 9 + 2];
        float c10 = cov3d[n * 9 + 3], c11 = cov3d[n * 9 + 4], c12 = cov3d[n * 9 + 5];
        float c20 = cov3d[n * 9 + 6], c21 = cov3d[n * 9 + 7], c22 = cov3d[n * 9 + 8];
        for (int vv = 0; vv <= v; ++vv) {
            float s01 = 0.5f * (c01 + c10);
            float s02 = 0.5f * (c02 + c20);
            float s12 = 0.5f * (c12 + c21);
            float s00 = c00 + 1e-6f;
            float s11 = c11 + 1e-6f;
            float s22 = c22 + 1e-6f;
            float nrm = sqrtf(s00 * s00 + s11 * s11 + s22 * s22 +
                              2.0f * (s01 * s01 + s02 * s02 + s12 * s12));
            float inv = 1.0f / (nrm + 1e-6f);
            c00 = s00 * inv; c11 = s11 * inv; c22 = s22 * inv;
            c01 = s01 * inv; c10 = c01; c02 = s02 * inv; c20 = c02;
            c12 = s12 * inv; c21 = c12;
        }
        float cof00 = c11 * c22 - c12 * c12;
        float cof01 = c02 * c12 - c01 * c22;
        float cof02 = c01 * c12 - c02 * c11;
        float det = c00 * cof00 + c01 * cof01 + c02 * cof02;
        float idet = 1.0f / det;
        float i00 = cof00 * idet;
        float i01 = cof01 * idet;
        float i02 = cof02 * idet;
        float i11 = (c00 * c22 - c02 * c02) * idet;
        float i12 = (c02 * c01 - c00 * c12) * idet;
        float i22 = (c00 * c11 - c01 * c01) * idet;

        float Aa, Ab, Ac, prx, pry;
        if (v == 0)      { Aa = i00; Ab = i01; Ac = i11; prx = p0; pry = p1; }
        else if (v == 1) { Aa = i00; Ab = i02; Ac = i22; prx = p0; pry = p2; }
        else             { Aa = i22; Ab = i12; Ac = i11; prx = p2; pry = p1; }
        Aa += 1e-10f;
        Ac += 1e-10f;
        float gx = fminf(fmaxf((prx - mnx2) / rngx * 111.0f, 0.0f), 111.0f);
        float gy = fminf(fmaxf((pry - mny2) / rngy * 111.0f, 0.0f), 111.0f);

        float dx = fmaxf(fmaxf(bx0 - gx, gx - bx1), 0.0f);
        float dy = fmaxf(fmaxf(by0 - gy, gy - by1), 0.0f);
        bool pass = (dx * dx + dy * dy) < 400.01f;  // conservative superset
        unsigned long long m = __ballot(pass);
        int base = 0;
        if (lane == 0) base = atomicAdd(&sm.sp.cnt, __popcll(m));
        base = __shfl(base, 0);
        if (pass) {
            int slot = base + __popcll(m & ((1ull << lane) - 1ull));
            sm.sp.lsA[slot] = make_float4(Aa, 2.0f * Ab, Ac, opimp);
            sm.sp.lsB[slot] = make_float2(gx, gy);
        }
    }
    __syncthreads();
    const int len = sm.sp.cnt;

    const int qx = lane & 7, qy = lane >> 3;
    const int xh = (tx0 >> 1) + qx;
    const int yh = (ty0 >> 1) + qy;

    const int npad = (len + 15) & ~15;     // 0 if len==0 -> loop skips, dmv=0
    if (tid < npad - len) {  // no-op pad gaussians (mask always fails -> w=0)
        sm.sp.lsA[len + tid] = make_float4(1.0f, 0.0f, 1.0f, 0.0f);
        sm.sp.lsB[len + tid] = make_float2(1e9f, 1e9f);
    }
    __syncthreads();

    // per-parity constants (generic formula, preserves edge clamping exactly)
    float exA[2], eyA[2], VxA[2], VyA[2];
    #pragma unroll
    for (int p = 0; p < 2; ++p) {
        int xlo = xh - 1 + p; int xhi = min(xlo + 1, 111); xlo = max(xlo, 0);
        float wlo = p ? 0.75f : 0.25f, whi = 1.0f - wlo;
        exA[p] = wlo * (float)xlo + whi * (float)xhi;
        VxA[p] = wlo * whi * (float)(xhi - xlo) * (float)(xhi - xlo);
        int ylo = yh - 1 + p; int yhi2 = min(ylo + 1, 111); ylo = max(ylo, 0);
        eyA[p] = wlo * (float)ylo + whi * (float)yhi2;
        VyA[p] = wlo * whi * (float)(yhi2 - ylo) * (float)(yhi2 - ylo);
    }
    const float fxh = (float)xh, fyh = (float)yh;

    // list chunk for this wave (4 waves -> npad/4 each; multiple of 4)
    const int chunk = npad >> 2;
    const int cbeg = wave * chunk, cend = cbeg + chunk;

    float S00 = 0.f, S01 = 0.f, S10 = 0.f, S11 = 0.f;
    float mn00 = INFINITY, mn01 = INFINITY, mn10 = INFINITY, mn11 = INFINITY;
    float mx00 = -INFINITY, mx01 = -INFINITY, mx10 = -INFINITY, mx11 = -INFINITY;

    for (int i = cbeg; i < cend; i += 2) {
        float4 gA0 = sm.sp.lsA[i], gA1 = sm.sp.lsA[i + 1];
        float2 gB0 = sm.sp.lsB[i], gB1 = sm.sp.lsB[i + 1];
        #pragma unroll
        for (int u = 0; u < 2; ++u) {
            const float4 gA = u ? gA1 : gA0;
            const float2 gB = u ? gB1 : gB0;
            const float a = gA.x, b2 = gA.y, c = gA.z, op = gA.w;
            const float xx = gB.x, yy = gB.y;
            const float dxh = fxh - xx, dyh = fyh - yy;
            const bool inside = dxh * dxh + dyh * dyh < 400.0f;
            const float dx0 = exA[0] - xx, dx1 = exA[1] - xx;
            const float dy0 = eyA[0] - yy, dy1 = eyA[1] - yy;
            const float adx0 = a * dx0, adx1 = a * dx1;
            const float bdy0 = b2 * dy0, bdy1 = b2 * dy1;
            const float cdy0 = c * dy0 * dy0, cdy1 = c * dy1 * dy1;
            const float ax0 = a * VxA[0], ax1 = a * VxA[1];
            const float cy0 = c * VyA[0], cy1 = c * VyA[1];
            #pragma unroll
            for (int py = 0; py < 2; ++py) {
                const float dyp  = py ? dy1 : dy0;
                const float bdyp = py ? bdy1 : bdy0;
                const float cdyp = py ? cdy1 : cdy0;
                const float cyp  = py ? cy1 : cy0;
                (void)dyp;
                #pragma unroll
                for (int px = 0; px < 2; ++px) {
                    const float dxp  = px ? dx1 : dx0;
                    const float adxp = px ? adx1 : adx0;
                    const float axp  = px ? ax1 : ax0;
                    float q = dxp * (adxp + bdyp) + cdyp;
                    float bil = -((q + axp) + cyp);
                    bil = fminf(fmaxf(bil, -20.0f), 0.0f);
                    bil = inside ? bil : -1e9f;   // exp flushes to +0
                    float w = op * __expf(bil);
                    if (py == 0 && px == 0) { S00 += w; mn00 = fminf(mn00, w); mx00 = fmaxf(mx00, w); }
                    if (py == 0 && px == 1) { S01 += w; mn01 = fminf(mn01, w); mx01 = fmaxf(mx01, w); }
                    if (py == 1 && px == 0) { S10 += w; mn10 = fminf(mn10, w); mx10 = fmaxf(mx10, w); }
                    if (py == 1 && px == 1) { S11 += w; mn11 = fminf(mn11, w); mx11 = fmaxf(mx11, w); }
                }
            }
        }
    }
    if (wave > 0) {
        sm.sp.pS[wave - 1][lane]  = make_float4(S00, S01, S10, S11);
        sm.sp.pMn[wave - 1][lane] = make_float4(mn00, mn01, mn10, mn11);
        sm.sp.pMx[wave - 1][lane] = make_float4(mx00, mx01, mx10, mx11);
    }
    __syncthreads();
    if (wave == 0) {
        #pragma unroll
        for (int k = 0; k < 3; ++k) {
            float4 s = sm.sp.pS[k][lane], m = sm.sp.pMn[k][lane], M = sm.sp.pMx[k][lane];
            S00 += s.x; S01 += s.y; S10 += s.z; S11 += s.w;
            mn00 = fminf(mn00, m.x); mn01 = fminf(mn01, m.y);
            mn10 = fminf(mn10, m.z); mn11 = fminf(mn11, m.w);
            mx00 = fmaxf(mx00, M.x); mx01 = fmaxf(mx01, M.y);
            mx10 = fmaxf(mx10, M.z); mx11 = fmaxf(mx11, M.w);
        }
        if (len < 512) {
            mn00 = fminf(mn00, 0.f); mn01 = fminf(mn01, 0.f);
            mn10 = fminf(mn10, 0.f); mn11 = fminf(mn11, 0.f);
            mx00 = fmaxf(mx00, 0.f); mx01 = fmaxf(mx01, 0.f);
            mx10 = fmaxf(mx10, 0.f); mx11 = fmaxf(mx11, 0.f);
        }
        float S4[4]  = {S00, S01, S10, S11};
        float mn4[4] = {mn00, mn01, mn10, mn11};
        float mx4[4] = {mx00, mx01, mx10, mx11};
        #pragma unroll
        for (int pp = 0; pp < 4; ++pp) {
            float S = S4[pp];
            float dmv = 0.5f * (S - 512.0f * mn4[pp]) / (mx4[pp] - mn4[pp] + 1e-6f)
                      + S / (S + 1e-6f);
            const int py = pp >> 1, px = pp & 1;
            dm[(v * 224 + ty0 + 2 * qy + py) * 224 + tx0 + 2 * qx + px] = dmv;
        }
    }

    gg.sync();  // all dm tiles visible device-wide

    // ================= phase 2: blur2 + partial stats =================
    const float kw[7] = {0.00443305f, 0.05400558f, 0.24203623f, 0.39905030f,
                         0.24203623f, 0.05400558f, 0.00443305f};
    const float* __restrict__ chan = dm + v * 224 * 224;

    for (int idx = tid; idx < 28 * 28; idx += 256) {
        int rr = idx / 28, c = idx % 28;
        int gyy = ty0 - 6 + rr, gxx = tx0 - 6 + c;
        float val = 0.0f;
        if (gyy >= 0 && gyy < 224 && gxx >= 0 && gxx < 224) val = chan[gyy * 224 + gxx];
        sm.bl.A[rr * 29 + c] = val;
    }
    __syncthreads();
    for (int idx = tid; idx < 22 * 28; idx += 256) {
        int rr = 3 + idx / 28, c = idx % 28;
        float s = 0.0f;
        #pragma unroll
        for (int i = 0; i < 7; ++i) s += kw[i] * sm.bl.A[(rr - 3 + i) * 29 + c];
        sm.bl.T[rr * 29 + c] = s;
    }
    __syncthreads();
    for (int idx = tid; idx < 22 * 22; idx += 256) {
        int rr = 3 + idx / 22, c = 3 + idx % 22;
        int gyy = ty0 - 6 + rr, gxx = tx0 - 6 + c;
        float s = 0.0f;
        #pragma unroll
        for (int j = 0; j < 7; ++j) s += kw[j] * sm.bl.T[rr * 29 + c - 3 + j];
        float ctr = sm.bl.A[rr * 29 + c];
        float d1 = ctr > 1e-6f ? ctr : s;
        if (gyy < 0 || gyy > 223 || gxx < 0 || gxx > 223) d1 = 0.0f;
        sm.bl.A[rr * 29 + c] = d1;
    }
    __syncthreads();
    for (int idx = tid; idx < 16 * 22; idx += 256) {
        int rr = 6 + idx / 22, c = 3 + idx % 22;
        float s = 0.0f;
        #pragma unroll
        for (int i = 0; i < 7; ++i) s += kw[i] * sm.bl.A[(rr - 3 + i) * 29 + c];
        sm.bl.T[rr * 29 + c] = s;
    }
    __syncthreads();
    // one output px per thread; KEEP d2 in a register for phase 3
    const int rr2 = 6 + (tid >> 4), cc2 = 6 + (tid & 15);
    float d2;
    {
        float s = 0.0f;
        #pragma unroll
        for (int j = 0; j < 7; ++j) s += kw[j] * sm.bl.T[rr2 * 29 + cc2 - 3 + j];
        float ctr = sm.bl.A[rr2 * 29 + cc2];
        d2 = ctr > 1e-6f ? ctr : s;
    }
    float ls1 = d2, ls2 = d2 * d2;
    #pragma unroll
    for (int o = 32; o >= 1; o >>= 1) {
        ls1 += __shfl_xor(ls1, o);
        ls2 += __shfl_xor(ls2, o);
    }
    if (lane == 0) { sm.bl.r1[wave] = ls1; sm.bl.r2[wave] = ls2; }
    __syncthreads();
    if (tid == 0) {
        float s1 = sm.bl.r1[0] + sm.bl.r1[1] + sm.bl.r1[2] + sm.bl.r1[3];
        float s2 = sm.bl.r2[0] + sm.bl.r2[1] + sm.bl.r2[2] + sm.bl.r2[3];
        partials[(v * 14 + blockIdx.y) * 14 + blockIdx.x] = make_float2(s1, s2);
    }

    gg.sync();  // all partials visible device-wide

    // ================= phase 3: normalize (from registers) =================
    double a = 0.0, b = 0.0;
    for (int i = tid; i < 588; i += 256) {
        float2 p = partials[i];
        a += (double)p.x; b += (double)p.y;
    }
    sm.nm.s1[tid] = a; sm.nm.s2[tid] = b;
    __syncthreads();
    for (int s = 128; s >= 1; s >>= 1) {
        if (tid < s) { sm.nm.s1[tid] += sm.nm.s1[tid + s]; sm.nm.s2[tid] += sm.nm.s2[tid + s]; }
        __syncthreads();
    }
    const double M = 150528.0;
    double mean = sm.nm.s1[0] / M;
    double var = (sm.nm.s2[0] - M * mean * mean) / (M - 1.0);
    double sd = sqrt(var > 0.0 ? var : 0.0);
    out[(v * 224 + ty0 + (tid >> 4)) * 224 + tx0 + (tid & 15)] =
        (d2 - (float)mean) / ((float)sd + 1e-6f);
}

// ===========================================================================
// Fallback path: the proven 3-kernel pipeline (verbatim from R5 best kernel),
// used only if the cooperative launch is rejected by the runtime.
// ===========================================================================

__global__ __launch_bounds__(512) void splat_fused_kernel(
    const float* __restrict__ position, const float* __restrict__ cov3d,
    const float* __restrict__ opacity, const float* __restrict__ importance,
    float* __restrict__ dm) {
    __shared__ float4 lsA[512];
    __shared__ float2 lsB[512];
    __shared__ float red[8 * 6];
    __shared__ float4 pS[7][64], pMn[7][64], pMx[7][64];
    __shared__ int cnt;
    const int v = blockIdx.z;
    const int tx0 = blockIdx.x * 16, ty0 = blockIdx.y * 16;
    const int tid = threadIdx.x;
    const int lane = tid & 63, wave = tid >> 6;

    const int n = tid;
    const float p0 = position[n * 3 + 0];
    const float p1 = position[n * 3 + 1];
    const float p2 = position[n * 3 + 2];
    const float opimp = opacity[n] * fminf(fmaxf(importance[n], 0.5f), 2.0f);

    {
        float vals[6] = {p0, -p0, p1, -p1, p2, -p2};
        #pragma unroll
        for (int k = 0; k < 6; ++k) {
            float r = wave_min(vals[k]);
            if (lane == 0) red[wave * 6 + k] = r;
        }
    }
    __syncthreads();
    float mn6[6];
    #pragma unroll
    for (int k = 0; k < 6; ++k) {
        float r = red[k];
        #pragma unroll
        for (int w = 1; w < 8; ++w) r = fminf(r, red[w * 6 + k]);
        mn6[k] = r;
    }
    const float pmn[3] = {mn6[0], mn6[2], mn6[4]};
    const float pmx[3] = {-mn6[1], -mn6[3], -mn6[5]};

    float c00 = cov3d[n * 9 + 0], c01 = cov3d[n * 9 + 1], c02 = cov3d[n * 9 + 2];
    float c10 = cov3d[n * 9 + 3], c11 = cov3d[n * 9 + 4], c12 = cov3d[n * 9 + 5];
    float c20 = cov3d[n * 9 + 6], c21 = cov3d[n * 9 + 7], c22 = cov3d[n * 9 + 8];
    for (int vv = 0; vv <= v; ++vv) {
        float s01 = 0.5f * (c01 + c10);
        float s02 = 0.5f * (c02 + c20);
        float s12 = 0.5f * (c12 + c21);
        float s00 = c00 + 1e-6f;
        float s11 = c11 + 1e-6f;
        float s22 = c22 + 1e-6f;
        float nrm = sqrtf(s00 * s00 + s11 * s11 + s22 * s22 +
                          2.0f * (s01 * s01 + s02 * s02 + s12 * s12));
        float inv = 1.0f / (nrm + 1e-6f);
        c00 = s00 * inv; c11 = s11 * inv; c22 = s22 * inv;
        c01 = s01 * inv; c10 = c01; c02 = s02 * inv; c20 = c02;
        c12 = s12 * inv; c21 = c12;
    }
    float cof00 = c11 * c22 - c12 * c12;
    float cof01 = c02 * c12 - c01 * c22;
    float cof02 = c01 * c12 - c02 * c11;
    float det = c00 * cof00 + c01 * cof01 + c02 * cof02;
    float idet = 1.0f / det;
    float i00 = cof00 * idet;
    float i01 = cof01 * idet;
    float i02 = cof02 * idet;
    float i11 = (c00 * c22 - c02 * c02) * idet;
    float i12 = (c02 * c01 - c00 * c12) * idet;
    float i22 = (c00 * c11 - c01 * c01) * idet;

    float Aa, Ab, Ac, prx, pry;
    int ix, iy;
    if (v == 0)      { Aa = i00; Ab = i01; Ac = i11; prx = p0; pry = p1; ix = 0; iy = 1; }
    else if (v == 1) { Aa = i00; Ab = i02; Ac = i22; prx = p0; pry = p2; ix = 0; iy = 2; }
    else             { Aa = i22; Ab = i12; Ac = i11; prx = p2; pry = p1; ix = 2; iy = 1; }
    Aa += 1e-10f;
    Ac += 1e-10f;

    float mnx = pmn[ix], mxx = pmx[ix], mny = pmn[iy], mxy = pmx[iy];
    float rngx = mxx - mnx + 1e-6f;
    float mnx2 = mnx - 0.5f * rngx;
    float mxx2 = mxx + 0.5f * rngx;
    rngx = mxx2 - mnx2 + 1e-6f;
    float rngy = mxy - mny + 1e-6f;
    float mny2 = mny - 0.5f * rngy;
    float mxy2 = mxy + 0.5f * rngy;
    rngy = mxy2 - mny2 + 1e-6f;
    float gx = fminf(fmaxf((prx - mnx2) / rngx * 111.0f, 0.0f), 111.0f);
    float gy = fminf(fmaxf((pry - mny2) / rngy * 111.0f, 0.0f), 111.0f);

    if (tid == 0) cnt = 0;
    __syncthreads();
    {
        const float bx0 = (float)(tx0 >> 1), bx1 = (float)((tx0 + 15) >> 1);
        const float by0 = (float)(ty0 >> 1), by1 = (float)((ty0 + 15) >> 1);
        float dx = fmaxf(fmaxf(bx0 - gx, gx - bx1), 0.0f);
        float dy = fmaxf(fmaxf(by0 - gy, gy - by1), 0.0f);
        bool pass = (dx * dx + dy * dy) < 400.01f;
        unsigned long long m = __ballot(pass);
        int base = 0;
        if (lane == 0) base = atomicAdd(&cnt, __popcll(m));
        base = __shfl(base, 0);
        if (pass) {
            int slot = base + __popcll(m & ((1ull << lane) - 1ull));
            lsA[slot] = make_float4(Aa, 2.0f * Ab, Ac, opimp);
            lsB[slot] = make_float2(gx, gy);
        }
    }
    __syncthreads();
    const int len = cnt;

    const int qx = lane & 7, qy = lane >> 3;
    const int xh = (tx0 >> 1) + qx;
    const int yh = (ty0 >> 1) + qy;

    if (len == 0) {
        if (wave == 0) {
            #pragma unroll
            for (int py = 0; py < 2; ++py)
                #pragma unroll
                for (int px = 0; px < 2; ++px)
                    dm[(v * 224 + ty0 + 2 * qy + py) * 224 + tx0 + 2 * qx + px] = 0.0f;
        }
        return;
    }

    const int npad = (len + 15) & ~15;
    if (tid < npad - len) {
        lsA[len + tid] = make_float4(1.0f, 0.0f, 1.0f, 0.0f);
        lsB[len + tid] = make_float2(1e9f, 1e9f);
    }
    __syncthreads();

    float exA[2], eyA[2], VxA[2], VyA[2];
    #pragma unroll
    for (int p = 0; p < 2; ++p) {
        int xlo = xh - 1 + p; int xhi = min(xlo + 1, 111); xlo = max(xlo, 0);
        float wlo = p ? 0.75f : 0.25f, whi = 1.0f - wlo;
        exA[p] = wlo * (float)xlo + whi * (float)xhi;
        VxA[p] = wlo * whi * (float)(xhi - xlo) * (float)(xhi - xlo);
        int ylo = yh - 1 + p; int yhi2 = min(ylo + 1, 111); ylo = max(ylo, 0);
        eyA[p] = wlo * (float)ylo + whi * (float)yhi2;
        VyA[p] = wlo * whi * (float)(yhi2 - ylo) * (float)(yhi2 - ylo);
    }
    const float fxh = (float)xh, fyh = (float)yh;

    const int chunk = npad >> 3;
    const int cbeg = wave * chunk, cend = cbeg + chunk;

    float S00 = 0.f, S01 = 0.f, S10 = 0.f, S11 = 0.f;
    float mn00 = INFINITY, mn01 = INFINITY, mn10 = INFINITY, mn11 = INFINITY;
    float mx00 = -INFINITY, mx01 = -INFINITY, mx10 = -INFINITY, mx11 = -INFINITY;

    for (int i = cbeg; i < cend; i += 2) {
        float4 gA0 = lsA[i], gA1 = lsA[i + 1];
        float2 gB0 = lsB[i], gB1 = lsB[i + 1];
        #pragma unroll
        for (int u = 0; u < 2; ++u) {
            const float4 gA = u ? gA1 : gA0;
            const float2 gB = u ? gB1 : gB0;
            const float a = gA.x, b2 = gA.y, c = gA.z, op = gA.w;
            const float xx = gB.x, yy = gB.y;
            const float dxh = fxh - xx, dyh = fyh - yy;
            const bool inside = dxh * dxh + dyh * dyh < 400.0f;
            const float dx0 = exA[0] - xx, dx1 = exA[1] - xx;
            const float dy0 = eyA[0] - yy, dy1 = eyA[1] - yy;
            const float adx0 = a * dx0, adx1 = a * dx1;
            const float bdy0 = b2 * dy0, bdy1 = b2 * dy1;
            const float cdy0 = c * dy0 * dy0, cdy1 = c * dy1 * dy1;
            const float ax0 = a * VxA[0], ax1 = a * VxA[1];
            const float cy0 = c * VyA[0], cy1 = c * VyA[1];
            #pragma unroll
            for (int py = 0; py < 2; ++py) {
                const float bdyp = py ? bdy1 : bdy0;
                const float cdyp = py ? cdy1 : cdy0;
                const float cyp  = py ? cy1 : cy0;
                #pragma unroll
                for (int px = 0; px < 2; ++px) {
                    const float dxp  = px ? dx1 : dx0;
                    const float adxp = px ? adx1 : adx0;
                    const float axp  = px ? ax1 : ax0;
                    float q = dxp * (adxp + bdyp) + cdyp;
                    float bil = -((q + axp) + cyp);
                    bil = fminf(fmaxf(bil, -20.0f), 0.0f);
                    bil = inside ? bil : -1e9f;
                    float w = op * __expf(bil);
                    if (py == 0 && px == 0) { S00 += w; mn00 = fminf(mn00, w); mx00 = fmaxf(mx00, w); }
                    if (py == 0 && px == 1) { S01 += w; mn01 = fminf(mn01, w); mx01 = fmaxf(mx01, w); }
                    if (py == 1 && px == 0) { S10 += w; mn10 = fminf(mn10, w); mx10 = fmaxf(mx10, w); }
                    if (py == 1 && px == 1) { S11 += w; mn11 = fminf(mn11, w); mx11 = fmaxf(mx11, w); }
                }
            }
        }
    }
    if (wave > 0) {
        pS[wave - 1][lane]  = make_float4(S00, S01, S10, S11);
        pMn[wave - 1][lane] = make_float4(mn00, mn01, mn10, mn11);
        pMx[wave - 1][lane] = make_float4(mx00, mx01, mx10, mx11);
    }
    __syncthreads();
    if (wave == 0) {
        #pragma unroll
        for (int k = 0; k < 7; ++k) {
            float4 s = pS[k][lane], m = pMn[k][lane], M = pMx[k][lane];
            S00 += s.x; S01 += s.y; S10 += s.z; S11 += s.w;
            mn00 = fminf(mn00, m.x); mn01 = fminf(mn01, m.y);
            mn10 = fminf(mn10, m.z); mn11 = fminf(mn11, m.w);
            mx00 = fmaxf(mx00, M.x); mx01 = fmaxf(mx01, M.y);
            mx10 = fmaxf(mx10, M.z); mx11 = fmaxf(mx11, M.w);
        }
        if (len < 512) {
            mn00 = fminf(mn00, 0.f); mn01 = fminf(mn01, 0.f);
            mn10 = fminf(mn10, 0.f); mn11 = fminf(mn11, 0.f);
            mx00 = fmaxf(mx00, 0.f); mx01 = fmaxf(mx01, 0.f);
            mx10 = fmaxf(mx10, 0.f); mx11 = fmaxf(mx11, 0.f);
        }
        float S4[4]  = {S00, S01, S10, S11};
        float mn4[4] = {mn00, mn01, mn10, mn11};
        float mx4[4] = {mx00, mx01, mx10, mx11};
        #pragma unroll
        for (int pp = 0; pp < 4; ++pp) {
            float S = S4[pp];
            float dmv = 0.5f * (S - 512.0f * mn4[pp]) / (mx4[pp] - mn4[pp] + 1e-6f)
                      + S / (S + 1e-6f);
            const int py = pp >> 1, px = pp & 1;
            dm[(v * 224 + ty0 + 2 * qy + py) * 224 + tx0 + 2 * qx + px] = dmv;
        }
    }
}

__global__ __launch_bounds__(256) void blur2_stats_kernel(
    const float* __restrict__ in, float* __restrict__ out,
    float2* __restrict__ partials) {
    __shared__ float A[28 * 29];
    __shared__ float T[28 * 29];
    __shared__ float r1[4], r2[4];
    const int v = blockIdx.z;
    const int tx0 = blockIdx.x * 16, ty0 = blockIdx.y * 16;
    const int tid = threadIdx.x;
    const float kw[7] = {0.00443305f, 0.05400558f, 0.24203623f, 0.39905030f,
                         0.24203623f, 0.05400558f, 0.00443305f};
    const float* __restrict__ chan = in + v * 224 * 224;

    for (int idx = tid; idx < 28 * 28; idx += 256) {
        int rr = idx / 28, c = idx % 28;
        int gyy = ty0 - 6 + rr, gxx = tx0 - 6 + c;
        float val = 0.0f;
        if (gyy >= 0 && gyy < 224 && gxx >= 0 && gxx < 224) val = chan[gyy * 224 + gxx];
        A[rr * 29 + c] = val;
    }
    __syncthreads();
    for (int idx = tid; idx < 22 * 28; idx += 256) {
        int rr = 3 + idx / 28, c = idx % 28;
        float s = 0.0f;
        #pragma unroll
        for (int i = 0; i < 7; ++i) s += kw[i] * A[(rr - 3 + i) * 29 + c];
        T[rr * 29 + c] = s;
    }
    __syncthreads();
    for (int idx = tid; idx < 22 * 22; idx += 256) {
        int rr = 3 + idx / 22, c = 3 + idx % 22;
        int gyy = ty0 - 6 + rr, gxx = tx0 - 6 + c;
        float s = 0.0f;
        #pragma unroll
        for (int j = 0; j < 7; ++j) s += kw[j] * T[rr * 29 + c - 3 + j];
        float ctr = A[rr * 29 + c];
        float d1 = ctr > 1e-6f ? ctr : s;
        if (gyy < 0 || gyy > 223 || gxx < 0 || gxx > 223) d1 = 0.0f;
        A[rr * 29 + c] = d1;
    }
    __syncthreads();
    for (int idx = tid; idx < 16 * 22; idx += 256) {
        int rr = 6 + idx / 22, c = 3 + idx % 22;
        float s = 0.0f;
        #pragma unroll
        for (int i = 0; i < 7; ++i) s += kw[i] * A[(rr - 3 + i) * 29 + c];
        T[rr * 29 + c] = s;
    }
    __syncthreads();
    float ls1 = 0.0f, ls2 = 0.0f;
    for (int idx = tid; idx < 16 * 16; idx += 256) {
        int rr = 6 + (idx >> 4), c = 6 + (idx & 15);
        float s = 0.0f;
        #pragma unroll
        for (int j = 0; j < 7; ++j) s += kw[j] * T[rr * 29 + c - 3 + j];
        float ctr = A[rr * 29 + c];
        float d2 = ctr > 1e-6f ? ctr : s;
        out[(v * 224 + ty0 + rr - 6) * 224 + (tx0 + c - 6)] = d2;
        ls1 += d2; ls2 += d2 * d2;
    }
    #pragma unroll
    for (int o = 32; o >= 1; o >>= 1) {
        ls1 += __shfl_xor(ls1, o);
        ls2 += __shfl_xor(ls2, o);
    }
    if ((tid & 63) == 0) { r1[tid >> 6] = ls1; r2[tid >> 6] = ls2; }
    __syncthreads();
    if (tid == 0) {
        float s1 = r1[0] + r1[1] + r1[2] + r1[3];
        float s2 = r2[0] + r2[1] + r2[2] + r2[3];
        partials[(blockIdx.z * 14 + blockIdx.y) * 14 + blockIdx.x] = make_float2(s1, s2);
    }
}

__global__ __launch_bounds__(256) void normalize_kernel(
    const float2* __restrict__ partials, float* __restrict__ out) {
    __shared__ double s1[256], s2[256];
    const int tid = threadIdx.x;
    double a = 0.0, b = 0.0;
    for (int i = tid; i < 588; i += 256) {
        float2 p = partials[i];
        a += (double)p.x; b += (double)p.y;
    }
    s1[tid] = a; s2[tid] = b;
    __syncthreads();
    for (int s = 128; s >= 1; s >>= 1) {
        if (tid < s) { s1[tid] += s1[tid + s]; s2[tid] += s2[tid + s]; }
        __syncthreads();
    }
    const double M = 150528.0;
    double mean = s1[0] / M;
    double var = (s2[0] - M * mean * mean) / (M - 1.0);
    double sd = sqrt(var > 0.0 ? var : 0.0);
    const int idx = blockIdx.x * 256 + tid;
    if (idx < 3 * 224 * 224)
        out[idx] = (out[idx] - (float)mean) / ((float)sd + 1e-6f);
}

extern "C" void kernel_launch(void* const* d_in, const int* in_sizes, int n_in,
                              void* d_out, int out_size, void* d_ws, size_t ws_size,
                              hipStream_t stream) {
    const float* position   = (const float*)d_in[0];  // (1,512,3)
    const float* cov3d      = (const float*)d_in[1];  // (1,512,3,3)
    const float* opacity    = (const float*)d_in[2];  // (1,512)
    const float* importance = (const float*)d_in[3];  // (1,1000)
    float* out = (float*)d_out;                       // (1,3,224,224)

    float* dmA       = (float*)d_ws;                  // 150528 floats
    float2* partials = (float2*)((float*)d_ws + 150528);  // 588 float2

    void* args[] = {(void*)&position, (void*)&cov3d, (void*)&opacity,
                    (void*)&importance, (void*)&dmA, (void*)&partials,
                    (void*)&out};
    hipError_t err = hipLaunchCooperativeKernel(
        reinterpret_cast<const void*>(&fused_all_kernel),
        dim3(14, 14, 3), dim3(256), args, 0, stream);
    if (err != hipSuccess) {
        // fallback: proven 3-kernel pipeline
        hipLaunchKernelGGL(splat_fused_kernel, dim3(14, 14, 3), dim3(512), 0, stream,
                           position, cov3d, opacity, importance, dmA);
        hipLaunchKernelGGL(blur2_stats_kernel, dim3(14, 14, 3), dim3(256), 0, stream,
                           dmA, out, partials);
        hipLaunchKernelGGL(normalize_kernel, dim3(588), dim3(256), 0, stream,
                           partials, out);
    }
}

// Round 2
// 120.732 us; speedup vs baseline: 1.6601x; 1.6601x over previous
//
#include <hip/hip_runtime.h>
#include <math.h>

// ---------------------------------------------------------------------------
// FullGaussianProjector: B=1, N=512, 3 views, 224x224 out, half-res 112x112.
// R7: single fused kernel with CUSTOM lightweight grid barrier.
//   R6 post-mortem: cg::grid sync cost ~120us (per-block L2 wb/inv across 8
//   XCDs, twice) and killed graph capture. Compute itself was only ~9us VALU.
//   Fix: all cross-block data (dm, partials) goes through relaxed AGENT-scope
//   atomics (LLC-coherent, bypass per-XCD L2) -> barrier needs NO cache
//   maintenance: s_waitcnt vmcnt(0) + relaxed atomicAdd + relaxed spin.
//   Non-cooperative launch (graph-capturable); co-residency guaranteed by
//   __launch_bounds__(256,3): 3 blocks/CU x 256 CU = 768 >= 588 (R6 measured
//   26% occupancy = all blocks resident). Counters zeroed per launch via 8-B
//   hipMemsetAsync. Tile permutation (5*b mod 14) spreads hot central tiles
//   across dispatch order for per-CU load balance.
//   phase 1 (splat): 2 gaussians/thread setup -> tile cull/compact -> 4 waves
//                    x 1/4-list chunks, lane owns a 2x2 px quad -> LDS merge.
//   phase 2 (blur):  2x (separable blur + where) in LDS; d2 stays in REGS.
//   phase 3 (norm):  all blocks reduce 588 partials (double), write out once.
// NOTE (R5 lesson): a,2b,c,op must stay f32 — bf16 on the exponent path
// fails absmax through the (wmax-wmin) normalization.
// ---------------------------------------------------------------------------

#define NBLOCKS 588u

__device__ __forceinline__ float g_ld(const float* p) {
    return __hip_atomic_load(p, __ATOMIC_RELAXED, __HIP_MEMORY_SCOPE_AGENT);
}
__device__ __forceinline__ void g_st(float* p, float v) {
    __hip_atomic_store(p, v, __ATOMIC_RELAXED, __HIP_MEMORY_SCOPE_AGENT);
}

// Lightweight grid barrier: no cache flush. Correctness relies on all
// cross-block traffic using agent-scope atomics (LLC is the coherence point;
// no block reads dm/partials lines before the barrier, so no stale copies).
__device__ __forceinline__ void grid_barrier(unsigned* cnt) {
    __syncthreads();
    if (threadIdx.x == 0) {
        asm volatile("s_waitcnt vmcnt(0)" ::: "memory");  // stores acked at LLC
        __hip_atomic_fetch_add(cnt, 1u, __ATOMIC_RELAXED, __HIP_MEMORY_SCOPE_AGENT);
        while (__hip_atomic_load(cnt, __ATOMIC_RELAXED, __HIP_MEMORY_SCOPE_AGENT) < NBLOCKS)
            __builtin_amdgcn_s_sleep(8);
    }
    __syncthreads();
}

__device__ __forceinline__ float wave_min(float v) {
    #pragma unroll
    for (int o = 32; o >= 1; o >>= 1) v = fminf(v, __shfl_xor(v, o));
    return v;
}

struct SpS {  // splat phase
    float4 lsA[512];        // a, 2b, c, op
    float2 lsB[512];        // gx, gy
    float4 pS[3][64], pMn[3][64], pMx[3][64];  // cross-wave merge (waves 1..3)
    float red[4 * 6];       // cross-wave min/max scratch
    int cnt;
};
struct BlS {  // blur phase
    float A[28 * 29];
    float T[28 * 29];
    float r1[4], r2[4];
};
struct NmS {  // normalize phase
    double s1[256], s2[256];
};
union SmU { SpS sp; BlS bl; NmS nm; };  // max ~21.6 KB

__global__ __launch_bounds__(256, 3) void fused_all_kernel(
    const float* __restrict__ position, const float* __restrict__ cov3d,
    const float* __restrict__ opacity, const float* __restrict__ importance,
    float* __restrict__ dm, float2* __restrict__ partials,
    float* __restrict__ out, unsigned* __restrict__ cnts) {
    __shared__ SmU sm;
    const int v = blockIdx.z;
    // bijective hot-tile spreading permutation: gcd(5,14)=1
    const int pbx = (5 * blockIdx.x) % 14;
    const int pby = (5 * blockIdx.y) % 14;
    const int tx0 = pbx * 16, ty0 = pby * 16;
    const int tid = threadIdx.x;
    const int lane = tid & 63, wave = tid >> 6;  // 4 waves

    // ================= phase 1: splat =================
    // setup: 2 gaussians per thread (n = tid, tid+256)
    float P0[3], P1[3], OP0, OP1;
    {
        const int n0 = tid, n1 = tid + 256;
        P0[0] = position[n0 * 3 + 0]; P0[1] = position[n0 * 3 + 1]; P0[2] = position[n0 * 3 + 2];
        P1[0] = position[n1 * 3 + 0]; P1[1] = position[n1 * 3 + 1]; P1[2] = position[n1 * 3 + 2];
        OP0 = opacity[n0] * fminf(fmaxf(importance[n0], 0.5f), 2.0f);
        OP1 = opacity[n1] * fminf(fmaxf(importance[n1], 0.5f), 2.0f);
    }
    if (tid == 0) sm.sp.cnt = 0;
    {
        float vals[6] = { fminf(P0[0], P1[0]), fminf(-P0[0], -P1[0]),
                          fminf(P0[1], P1[1]), fminf(-P0[1], -P1[1]),
                          fminf(P0[2], P1[2]), fminf(-P0[2], -P1[2]) };
        #pragma unroll
        for (int k = 0; k < 6; ++k) {
            float r = wave_min(vals[k]);
            if (lane == 0) sm.sp.red[wave * 6 + k] = r;
        }
    }
    __syncthreads();
    float mn6[6];
    #pragma unroll
    for (int k = 0; k < 6; ++k) {
        float r = sm.sp.red[k];
        #pragma unroll
        for (int w = 1; w < 4; ++w) r = fminf(r, sm.sp.red[w * 6 + k]);
        mn6[k] = r;
    }
    const float pmn[3] = {mn6[0], mn6[2], mn6[4]};
    const float pmx[3] = {-mn6[1], -mn6[3], -mn6[5]};
    int ix, iy;
    if (v == 0)      { ix = 0; iy = 1; }
    else if (v == 1) { ix = 0; iy = 2; }
    else             { ix = 2; iy = 1; }
    float mnx = pmn[ix], mxx = pmx[ix], mny = pmn[iy], mxy = pmx[iy];
    float rngx = mxx - mnx + 1e-6f;
    float mnx2 = mnx - 0.5f * rngx;
    float mxx2 = mxx + 0.5f * rngx;
    rngx = mxx2 - mnx2 + 1e-6f;
    float rngy = mxy - mny + 1e-6f;
    float mny2 = mny - 0.5f * rngy;
    float mxy2 = mxy + 0.5f * rngy;
    rngy = mxy2 - mny2 + 1e-6f;
    const float bx0 = (float)(tx0 >> 1), bx1 = (float)((tx0 + 15) >> 1);
    const float by0 = (float)(ty0 >> 1), by1 = (float)((ty0 + 15) >> 1);

    // cull + compact, 2 passes (math verbatim from verified version)
    for (int g = 0; g < 2; ++g) {
        const int n = tid + (g << 8);
        const float p0 = g ? P1[0] : P0[0];
        const float p1 = g ? P1[1] : P0[1];
        const float p2 = g ? P1[2] : P0[2];
        const float opimp = g ? OP1 : OP0;
        float c00 = cov3d[n * 9 + 0], c01 = cov3d[n * 9 + 1], c02 = cov3d[n * 9 + 2];
        float c10 = cov3d[n * 9 + 3], c11 = cov3d[n * 9 + 4], c12 = cov3d[n * 9 + 5];
        float c20 = cov3d[n * 9 + 6], c21 = cov3d[n * 9 + 7], c22 = cov3d[n * 9 + 8];
        for (int vv = 0; vv <= v; ++vv) {
            float s01 = 0.5f * (c01 + c10);
            float s02 = 0.5f * (c02 + c20);
            float s12 = 0.5f * (c12 + c21);
            float s00 = c00 + 1e-6f;
            float s11 = c11 + 1e-6f;
            float s22 = c22 + 1e-6f;
            float nrm = sqrtf(s00 * s00 + s11 * s11 + s22 * s22 +
                              2.0f * (s01 * s01 + s02 * s02 + s12 * s12));
            float inv = 1.0f / (nrm + 1e-6f);
            c00 = s00 * inv; c11 = s11 * inv; c22 = s22 * inv;
            c01 = s01 * inv; c10 = c01; c02 = s02 * inv; c20 = c02;
            c12 = s12 * inv; c21 = c12;
        }
        float cof00 = c11 * c22 - c12 * c12;
        float cof01 = c02 * c12 - c01 * c22;
        float cof02 = c01 * c12 - c02 * c11;
        float det = c00 * cof00 + c01 * cof01 + c02 * cof02;
        float idet = 1.0f / det;
        float i00 = cof00 * idet;
        float i01 = cof01 * idet;
        float i02 = cof02 * idet;
        float i11 = (c00 * c22 - c02 * c02) * idet;
        float i12 = (c02 * c01 - c00 * c12) * idet;
        float i22 = (c00 * c11 - c01 * c01) * idet;

        float Aa, Ab, Ac, prx, pry;
        if (v == 0)      { Aa = i00; Ab = i01; Ac = i11; prx = p0; pry = p1; }
        else if (v == 1) { Aa = i00; Ab = i02; Ac = i22; prx = p0; pry = p2; }
        else             { Aa = i22; Ab = i12; Ac = i11; prx = p2; pry = p1; }
        Aa += 1e-10f;
        Ac += 1e-10f;
        float gx = fminf(fmaxf((prx - mnx2) / rngx * 111.0f, 0.0f), 111.0f);
        float gy = fminf(fmaxf((pry - mny2) / rngy * 111.0f, 0.0f), 111.0f);

        float dx = fmaxf(fmaxf(bx0 - gx, gx - bx1), 0.0f);
        float dy = fmaxf(fmaxf(by0 - gy, gy - by1), 0.0f);
        bool pass = (dx * dx + dy * dy) < 400.01f;  // conservative superset
        unsigned long long m = __ballot(pass);
        int base = 0;
        if (lane == 0) base = atomicAdd(&sm.sp.cnt, __popcll(m));
        base = __shfl(base, 0);
        if (pass) {
            int slot = base + __popcll(m & ((1ull << lane) - 1ull));
            sm.sp.lsA[slot] = make_float4(Aa, 2.0f * Ab, Ac, opimp);
            sm.sp.lsB[slot] = make_float2(gx, gy);
        }
    }
    __syncthreads();
    const int len = sm.sp.cnt;

    const int qx = lane & 7, qy = lane >> 3;
    const int xh = (tx0 >> 1) + qx;
    const int yh = (ty0 >> 1) + qy;

    const int npad = (len + 15) & ~15;     // 0 if len==0 -> loop skips, dmv=0
    if (tid < npad - len) {  // no-op pad gaussians (mask always fails -> w=0)
        sm.sp.lsA[len + tid] = make_float4(1.0f, 0.0f, 1.0f, 0.0f);
        sm.sp.lsB[len + tid] = make_float2(1e9f, 1e9f);
    }
    __syncthreads();

    // per-parity constants (generic formula, preserves edge clamping exactly)
    float exA[2], eyA[2], VxA[2], VyA[2];
    #pragma unroll
    for (int p = 0; p < 2; ++p) {
        int xlo = xh - 1 + p; int xhi = min(xlo + 1, 111); xlo = max(xlo, 0);
        float wlo = p ? 0.75f : 0.25f, whi = 1.0f - wlo;
        exA[p] = wlo * (float)xlo + whi * (float)xhi;
        VxA[p] = wlo * whi * (float)(xhi - xlo) * (float)(xhi - xlo);
        int ylo = yh - 1 + p; int yhi2 = min(ylo + 1, 111); ylo = max(ylo, 0);
        eyA[p] = wlo * (float)ylo + whi * (float)yhi2;
        VyA[p] = wlo * whi * (float)(yhi2 - ylo) * (float)(yhi2 - ylo);
    }
    const float fxh = (float)xh, fyh = (float)yh;

    // list chunk for this wave (4 waves -> npad/4 each; multiple of 4)
    const int chunk = npad >> 2;
    const int cbeg = wave * chunk, cend = cbeg + chunk;

    float S00 = 0.f, S01 = 0.f, S10 = 0.f, S11 = 0.f;
    float mn00 = INFINITY, mn01 = INFINITY, mn10 = INFINITY, mn11 = INFINITY;
    float mx00 = -INFINITY, mx01 = -INFINITY, mx10 = -INFINITY, mx11 = -INFINITY;

    for (int i = cbeg; i < cend; i += 2) {
        float4 gA0 = sm.sp.lsA[i], gA1 = sm.sp.lsA[i + 1];
        float2 gB0 = sm.sp.lsB[i], gB1 = sm.sp.lsB[i + 1];
        #pragma unroll
        for (int u = 0; u < 2; ++u) {
            const float4 gA = u ? gA1 : gA0;
            const float2 gB = u ? gB1 : gB0;
            const float a = gA.x, b2 = gA.y, c = gA.z, op = gA.w;
            const float xx = gB.x, yy = gB.y;
            const float dxh = fxh - xx, dyh = fyh - yy;
            const bool inside = dxh * dxh + dyh * dyh < 400.0f;
            const float dx0 = exA[0] - xx, dx1 = exA[1] - xx;
            const float dy0 = eyA[0] - yy, dy1 = eyA[1] - yy;
            const float adx0 = a * dx0, adx1 = a * dx1;
            const float bdy0 = b2 * dy0, bdy1 = b2 * dy1;
            const float cdy0 = c * dy0 * dy0, cdy1 = c * dy1 * dy1;
            const float ax0 = a * VxA[0], ax1 = a * VxA[1];
            const float cy0 = c * VyA[0], cy1 = c * VyA[1];
            #pragma unroll
            for (int py = 0; py < 2; ++py) {
                const float bdyp = py ? bdy1 : bdy0;
                const float cdyp = py ? cdy1 : cdy0;
                const float cyp  = py ? cy1 : cy0;
                #pragma unroll
                for (int px = 0; px < 2; ++px) {
                    const float dxp  = px ? dx1 : dx0;
                    const float adxp = px ? adx1 : adx0;
                    const float axp  = px ? ax1 : ax0;
                    float q = dxp * (adxp + bdyp) + cdyp;
                    float bil = -((q + axp) + cyp);
                    bil = fminf(fmaxf(bil, -20.0f), 0.0f);
                    bil = inside ? bil : -1e9f;   // exp flushes to +0
                    float w = op * __expf(bil);
                    if (py == 0 && px == 0) { S00 += w; mn00 = fminf(mn00, w); mx00 = fmaxf(mx00, w); }
                    if (py == 0 && px == 1) { S01 += w; mn01 = fminf(mn01, w); mx01 = fmaxf(mx01, w); }
                    if (py == 1 && px == 0) { S10 += w; mn10 = fminf(mn10, w); mx10 = fmaxf(mx10, w); }
                    if (py == 1 && px == 1) { S11 += w; mn11 = fminf(mn11, w); mx11 = fmaxf(mx11, w); }
                }
            }
        }
    }
    if (wave > 0) {
        sm.sp.pS[wave - 1][lane]  = make_float4(S00, S01, S10, S11);
        sm.sp.pMn[wave - 1][lane] = make_float4(mn00, mn01, mn10, mn11);
        sm.sp.pMx[wave - 1][lane] = make_float4(mx00, mx01, mx10, mx11);
    }
    __syncthreads();
    if (wave == 0) {
        #pragma unroll
        for (int k = 0; k < 3; ++k) {
            float4 s = sm.sp.pS[k][lane], m = sm.sp.pMn[k][lane], M = sm.sp.pMx[k][lane];
            S00 += s.x; S01 += s.y; S10 += s.z; S11 += s.w;
            mn00 = fminf(mn00, m.x); mn01 = fminf(mn01, m.y);
            mn10 = fminf(mn10, m.z); mn11 = fminf(mn11, m.w);
            mx00 = fmaxf(mx00, M.x); mx01 = fmaxf(mx01, M.y);
            mx10 = fmaxf(mx10, M.z); mx11 = fmaxf(mx11, M.w);
        }
        if (len < 512) {
            mn00 = fminf(mn00, 0.f); mn01 = fminf(mn01, 0.f);
            mn10 = fminf(mn10, 0.f); mn11 = fminf(mn11, 0.f);
            mx00 = fmaxf(mx00, 0.f); mx01 = fmaxf(mx01, 0.f);
            mx10 = fmaxf(mx10, 0.f); mx11 = fmaxf(mx11, 0.f);
        }
        float S4[4]  = {S00, S01, S10, S11};
        float mn4[4] = {mn00, mn01, mn10, mn11};
        float mx4[4] = {mx00, mx01, mx10, mx11};
        #pragma unroll
        for (int pp = 0; pp < 4; ++pp) {
            float S = S4[pp];
            float dmv = 0.5f * (S - 512.0f * mn4[pp]) / (mx4[pp] - mn4[pp] + 1e-6f)
                      + S / (S + 1e-6f);
            const int py = pp >> 1, px = pp & 1;
            g_st(&dm[(v * 224 + ty0 + 2 * qy + py) * 224 + tx0 + 2 * qx + px], dmv);
        }
    }

    grid_barrier(&cnts[0]);  // all dm tiles visible at LLC

    // ================= phase 2: blur2 + partial stats =================
    const float kw[7] = {0.00443305f, 0.05400558f, 0.24203623f, 0.39905030f,
                         0.24203623f, 0.05400558f, 0.00443305f};
    const float* __restrict__ chan = dm + v * 224 * 224;

    for (int idx = tid; idx < 28 * 28; idx += 256) {
        int rr = idx / 28, c = idx % 28;
        int gyy = ty0 - 6 + rr, gxx = tx0 - 6 + c;
        float val = 0.0f;
        if (gyy >= 0 && gyy < 224 && gxx >= 0 && gxx < 224) val = g_ld(chan + gyy * 224 + gxx);
        sm.bl.A[rr * 29 + c] = val;
    }
    __syncthreads();
    for (int idx = tid; idx < 22 * 28; idx += 256) {
        int rr = 3 + idx / 28, c = idx % 28;
        float s = 0.0f;
        #pragma unroll
        for (int i = 0; i < 7; ++i) s += kw[i] * sm.bl.A[(rr - 3 + i) * 29 + c];
        sm.bl.T[rr * 29 + c] = s;
    }
    __syncthreads();
    for (int idx = tid; idx < 22 * 22; idx += 256) {
        int rr = 3 + idx / 22, c = 3 + idx % 22;
        int gyy = ty0 - 6 + rr, gxx = tx0 - 6 + c;
        float s = 0.0f;
        #pragma unroll
        for (int j = 0; j < 7; ++j) s += kw[j] * sm.bl.T[rr * 29 + c - 3 + j];
        float ctr = sm.bl.A[rr * 29 + c];
        float d1 = ctr > 1e-6f ? ctr : s;
        if (gyy < 0 || gyy > 223 || gxx < 0 || gxx > 223) d1 = 0.0f;
        sm.bl.A[rr * 29 + c] = d1;
    }
    __syncthreads();
    for (int idx = tid; idx < 16 * 22; idx += 256) {
        int rr = 6 + idx / 22, c = 3 + idx % 22;
        float s = 0.0f;
        #pragma unroll
        for (int i = 0; i < 7; ++i) s += kw[i] * sm.bl.A[(rr - 3 + i) * 29 + c];
        sm.bl.T[rr * 29 + c] = s;
    }
    __syncthreads();
    // one output px per thread; KEEP d2 in a register for phase 3
    const int rr2 = 6 + (tid >> 4), cc2 = 6 + (tid & 15);
    float d2;
    {
        float s = 0.0f;
        #pragma unroll
        for (int j = 0; j < 7; ++j) s += kw[j] * sm.bl.T[rr2 * 29 + cc2 - 3 + j];
        float ctr = sm.bl.A[rr2 * 29 + cc2];
        d2 = ctr > 1e-6f ? ctr : s;
    }
    float ls1 = d2, ls2 = d2 * d2;
    #pragma unroll
    for (int o = 32; o >= 1; o >>= 1) {
        ls1 += __shfl_xor(ls1, o);
        ls2 += __shfl_xor(ls2, o);
    }
    if (lane == 0) { sm.bl.r1[wave] = ls1; sm.bl.r2[wave] = ls2; }
    __syncthreads();
    if (tid == 0) {
        float s1 = sm.bl.r1[0] + sm.bl.r1[1] + sm.bl.r1[2] + sm.bl.r1[3];
        float s2 = sm.bl.r2[0] + sm.bl.r2[1] + sm.bl.r2[2] + sm.bl.r2[3];
        float* pb = (float*)&partials[(v * 14 + pby) * 14 + pbx];
        g_st(pb + 0, s1);
        g_st(pb + 1, s2);
    }

    grid_barrier(&cnts[1]);  // all partials visible at LLC

    // ================= phase 3: normalize (from registers) =================
    double a = 0.0, b = 0.0;
    const float* pb = (const float*)partials;
    for (int i = tid; i < 588; i += 256) {
        a += (double)g_ld(pb + 2 * i);
        b += (double)g_ld(pb + 2 * i + 1);
    }
    sm.nm.s1[tid] = a; sm.nm.s2[tid] = b;
    __syncthreads();
    for (int s = 128; s >= 1; s >>= 1) {
        if (tid < s) { sm.nm.s1[tid] += sm.nm.s1[tid + s]; sm.nm.s2[tid] += sm.nm.s2[tid + s]; }
        __syncthreads();
    }
    const double M = 150528.0;
    double mean = sm.nm.s1[0] / M;
    double var = (sm.nm.s2[0] - M * mean * mean) / (M - 1.0);
    double sd = sqrt(var > 0.0 ? var : 0.0);
    out[(v * 224 + ty0 + (tid >> 4)) * 224 + tx0 + (tid & 15)] =
        (d2 - (float)mean) / ((float)sd + 1e-6f);
}

extern "C" void kernel_launch(void* const* d_in, const int* in_sizes, int n_in,
                              void* d_out, int out_size, void* d_ws, size_t ws_size,
                              hipStream_t stream) {
    const float* position   = (const float*)d_in[0];  // (1,512,3)
    const float* cov3d      = (const float*)d_in[1];  // (1,512,3,3)
    const float* opacity    = (const float*)d_in[2];  // (1,512)
    const float* importance = (const float*)d_in[3];  // (1,1000)
    float* out = (float*)d_out;                       // (1,3,224,224)

    float* dmA       = (float*)d_ws;                          // 150528 floats
    float2* partials = (float2*)((float*)d_ws + 150528);      // 588 float2
    unsigned* cnts   = (unsigned*)((float*)d_ws + 150528 + 1176);  // 2 u32

    hipMemsetAsync(cnts, 0, 2 * sizeof(unsigned), stream);
    hipLaunchKernelGGL(fused_all_kernel, dim3(14, 14, 3), dim3(256), 0, stream,
                       position, cov3d, opacity, importance, dmA, partials, out,
                       cnts);
}

// Round 3
// 106.529 us; speedup vs baseline: 1.8814x; 1.1333x over previous
//
#include <hip/hip_runtime.h>
#include <math.h>

// ---------------------------------------------------------------------------
// FullGaussianProjector: B=1, N=512, 3 views, 224x224 out, half-res 112x112.
// R8: split along the uniformity boundary. 2 dispatches:
//   kernel 1 (splat, 512 thr): R0-proven per-tile cull/compact + quad eval.
//     NO grid barrier -> hardware dynamically rebalances the non-uniform
//     per-tile gaussian lists across CUs (R7 post-mortem: fused barrier
//     pinned 3 hot blocks to one CU = 21us serial tail; VALUBusy 13%).
//     Also clears the barrier counter for kernel 2 (kernel-boundary flush
//     orders it) -> no hipMemsetAsync dispatch.
//   kernel 2 (blur2 + stats + normalize, 256 thr): blur work is UNIFORM per
//     block, so the lightweight LLC grid barrier (agent-scope atomics +
//     s_waitcnt vmcnt(0) + relaxed spin; no cache maintenance) costs only
//     sync latency. d2 stays in registers across the barrier; out written
//     exactly once. dm read with plain loads (kernel boundary = coherence).
// NOTE (R5 lesson): a,2b,c,op must stay f32 — bf16 on the exponent path
// fails absmax through the (wmax-wmin) normalization.
// ---------------------------------------------------------------------------

#define NBLOCKS 588u

__device__ __forceinline__ float g_ld(const float* p) {
    return __hip_atomic_load(p, __ATOMIC_RELAXED, __HIP_MEMORY_SCOPE_AGENT);
}
__device__ __forceinline__ void g_st(float* p, float v) {
    __hip_atomic_store(p, v, __ATOMIC_RELAXED, __HIP_MEMORY_SCOPE_AGENT);
}

// Lightweight grid barrier: no cache flush. Correctness relies on all
// cross-block traffic through this barrier using agent-scope atomics (LLC is
// the coherence point; no block reads partials lines before the barrier).
__device__ __forceinline__ void grid_barrier(unsigned* cnt) {
    __syncthreads();
    if (threadIdx.x == 0) {
        asm volatile("s_waitcnt vmcnt(0)" ::: "memory");  // stores acked at LLC
        __hip_atomic_fetch_add(cnt, 1u, __ATOMIC_RELAXED, __HIP_MEMORY_SCOPE_AGENT);
        while (__hip_atomic_load(cnt, __ATOMIC_RELAXED, __HIP_MEMORY_SCOPE_AGENT) < NBLOCKS)
            __builtin_amdgcn_s_sleep(8);
    }
    __syncthreads();
}

__device__ __forceinline__ float wave_min(float v) {
    #pragma unroll
    for (int o = 32; o >= 1; o >>= 1) v = fminf(v, __shfl_xor(v, o));
    return v;
}

// Block: 512 threads (8 waves), tile 16x16 full-res px (8x8 quads), grid (14,14,3).
__global__ __launch_bounds__(512) void splat_fused_kernel(
    const float* __restrict__ position, const float* __restrict__ cov3d,
    const float* __restrict__ opacity, const float* __restrict__ importance,
    float* __restrict__ dm, unsigned* __restrict__ cnts) {
    __shared__ float4 lsA[512];        // a, 2b, c, op
    __shared__ float2 lsB[512];        // gx, gy
    __shared__ float red[8 * 6];       // cross-wave min/max scratch
    __shared__ float4 pS[7][64], pMn[7][64], pMx[7][64];
    __shared__ int cnt;
    const int v = blockIdx.z;
    const int tx0 = blockIdx.x * 16, ty0 = blockIdx.y * 16;
    const int tid = threadIdx.x;
    const int lane = tid & 63, wave = tid >> 6;

    // clear kernel-2 barrier counter (ws is poisoned each iteration; the
    // kernel boundary flush makes this visible before kernel 2 starts)
    if (blockIdx.x == 0 && blockIdx.y == 0 && blockIdx.z == 0 && tid == 0)
        cnts[0] = 0;

    // ---------------- setup (1 gaussian per thread) ----------------
    const int n = tid;
    const float p0 = position[n * 3 + 0];
    const float p1 = position[n * 3 + 1];
    const float p2 = position[n * 3 + 2];
    const float opimp = opacity[n] * fminf(fmaxf(importance[n], 0.5f), 2.0f);

    {
        float vals[6] = {p0, -p0, p1, -p1, p2, -p2};
        #pragma unroll
        for (int k = 0; k < 6; ++k) {
            float r = wave_min(vals[k]);
            if (lane == 0) red[wave * 6 + k] = r;
        }
    }
    __syncthreads();
    float mn6[6];
    #pragma unroll
    for (int k = 0; k < 6; ++k) {
        float r = red[k];
        #pragma unroll
        for (int w = 1; w < 8; ++w) r = fminf(r, red[w * 6 + k]);
        mn6[k] = r;
    }
    const float pmn[3] = {mn6[0], mn6[2], mn6[4]};
    const float pmx[3] = {-mn6[1], -mn6[3], -mn6[5]};

    float c00 = cov3d[n * 9 + 0], c01 = cov3d[n * 9 + 1], c02 = cov3d[n * 9 + 2];
    float c10 = cov3d[n * 9 + 3], c11 = cov3d[n * 9 + 4], c12 = cov3d[n * 9 + 5];
    float c20 = cov3d[n * 9 + 6], c21 = cov3d[n * 9 + 7], c22 = cov3d[n * 9 + 8];
    for (int vv = 0; vv <= v; ++vv) {
        float s01 = 0.5f * (c01 + c10);
        float s02 = 0.5f * (c02 + c20);
        float s12 = 0.5f * (c12 + c21);
        float s00 = c00 + 1e-6f;
        float s11 = c11 + 1e-6f;
        float s22 = c22 + 1e-6f;
        float nrm = sqrtf(s00 * s00 + s11 * s11 + s22 * s22 +
                          2.0f * (s01 * s01 + s02 * s02 + s12 * s12));
        float inv = 1.0f / (nrm + 1e-6f);
        c00 = s00 * inv; c11 = s11 * inv; c22 = s22 * inv;
        c01 = s01 * inv; c10 = c01; c02 = s02 * inv; c20 = c02;
        c12 = s12 * inv; c21 = c12;
    }
    float cof00 = c11 * c22 - c12 * c12;
    float cof01 = c02 * c12 - c01 * c22;
    float cof02 = c01 * c12 - c02 * c11;
    float det = c00 * cof00 + c01 * cof01 + c02 * cof02;
    float idet = 1.0f / det;
    float i00 = cof00 * idet;
    float i01 = cof01 * idet;
    float i02 = cof02 * idet;
    float i11 = (c00 * c22 - c02 * c02) * idet;
    float i12 = (c02 * c01 - c00 * c12) * idet;
    float i22 = (c00 * c11 - c01 * c01) * idet;

    float Aa, Ab, Ac, prx, pry;
    int ix, iy;
    if (v == 0)      { Aa = i00; Ab = i01; Ac = i11; prx = p0; pry = p1; ix = 0; iy = 1; }
    else if (v == 1) { Aa = i00; Ab = i02; Ac = i22; prx = p0; pry = p2; ix = 0; iy = 2; }
    else             { Aa = i22; Ab = i12; Ac = i11; prx = p2; pry = p1; ix = 2; iy = 1; }
    Aa += 1e-10f;
    Ac += 1e-10f;

    float mnx = pmn[ix], mxx = pmx[ix], mny = pmn[iy], mxy = pmx[iy];
    float rngx = mxx - mnx + 1e-6f;
    float mnx2 = mnx - 0.5f * rngx;
    float mxx2 = mxx + 0.5f * rngx;
    rngx = mxx2 - mnx2 + 1e-6f;
    float rngy = mxy - mny + 1e-6f;
    float mny2 = mny - 0.5f * rngy;
    float mxy2 = mxy + 0.5f * rngy;
    rngy = mxy2 - mny2 + 1e-6f;
    float gx = fminf(fmaxf((prx - mnx2) / rngx * 111.0f, 0.0f), 111.0f);
    float gy = fminf(fmaxf((pry - mny2) / rngy * 111.0f, 0.0f), 111.0f);

    // ---------------- cull + compact into LDS (SoA f32) ----------------
    if (tid == 0) cnt = 0;
    __syncthreads();
    {
        const float bx0 = (float)(tx0 >> 1), bx1 = (float)((tx0 + 15) >> 1);
        const float by0 = (float)(ty0 >> 1), by1 = (float)((ty0 + 15) >> 1);
        float dx = fmaxf(fmaxf(bx0 - gx, gx - bx1), 0.0f);
        float dy = fmaxf(fmaxf(by0 - gy, gy - by1), 0.0f);
        bool pass = (dx * dx + dy * dy) < 400.01f;  // conservative superset
        unsigned long long m = __ballot(pass);
        int base = 0;
        if (lane == 0) base = atomicAdd(&cnt, __popcll(m));
        base = __shfl(base, 0);
        if (pass) {
            int slot = base + __popcll(m & ((1ull << lane) - 1ull));
            lsA[slot] = make_float4(Aa, 2.0f * Ab, Ac, opimp);
            lsB[slot] = make_float2(gx, gy);
        }
    }
    __syncthreads();
    const int len = cnt;

    // quad owned by this lane: half-res pixel (xh, yh)
    const int qx = lane & 7, qy = lane >> 3;
    const int xh = (tx0 >> 1) + qx;
    const int yh = (ty0 >> 1) + qy;

    if (len == 0) {  // uniform branch: whole block exits
        if (wave == 0) {
            #pragma unroll
            for (int py = 0; py < 2; ++py)
                #pragma unroll
                for (int px = 0; px < 2; ++px)
                    dm[(v * 224 + ty0 + 2 * qy + py) * 224 + tx0 + 2 * qx + px] = 0.0f;
        }
        return;
    }

    const int npad = (len + 15) & ~15;
    if (tid < npad - len) {  // no-op pad gaussians (mask always fails -> w=0)
        lsA[len + tid] = make_float4(1.0f, 0.0f, 1.0f, 0.0f);
        lsB[len + tid] = make_float2(1e9f, 1e9f);
    }
    __syncthreads();

    // per-parity constants (generic formula, preserves edge clamping exactly)
    float exA[2], eyA[2], VxA[2], VyA[2];
    #pragma unroll
    for (int p = 0; p < 2; ++p) {
        int xlo = xh - 1 + p; int xhi = min(xlo + 1, 111); xlo = max(xlo, 0);
        float wlo = p ? 0.75f : 0.25f, whi = 1.0f - wlo;
        exA[p] = wlo * (float)xlo + whi * (float)xhi;
        VxA[p] = wlo * whi * (float)(xhi - xlo) * (float)(xhi - xlo);
        int ylo = yh - 1 + p; int yhi2 = min(ylo + 1, 111); ylo = max(ylo, 0);
        eyA[p] = wlo * (float)ylo + whi * (float)yhi2;
        VyA[p] = wlo * whi * (float)(yhi2 - ylo) * (float)(yhi2 - ylo);
    }
    const float fxh = (float)xh, fyh = (float)yh;

    // ---------------- list chunk for this wave, quad eval ----------------
    const int chunk = npad >> 3;           // multiple of 2
    const int cbeg = wave * chunk, cend = cbeg + chunk;

    float S00 = 0.f, S01 = 0.f, S10 = 0.f, S11 = 0.f;
    float mn00 = INFINITY, mn01 = INFINITY, mn10 = INFINITY, mn11 = INFINITY;
    float mx00 = -INFINITY, mx01 = -INFINITY, mx10 = -INFINITY, mx11 = -INFINITY;

    for (int i = cbeg; i < cend; i += 2) {
        float4 gA0 = lsA[i], gA1 = lsA[i + 1];
        float2 gB0 = lsB[i], gB1 = lsB[i + 1];
        #pragma unroll
        for (int u = 0; u < 2; ++u) {
            const float4 gA = u ? gA1 : gA0;
            const float2 gB = u ? gB1 : gB0;
            const float a = gA.x, b2 = gA.y, c = gA.z, op = gA.w;
            const float xx = gB.x, yy = gB.y;
            const float dxh = fxh - xx, dyh = fyh - yy;
            const bool inside = dxh * dxh + dyh * dyh < 400.0f;
            const float dx0 = exA[0] - xx, dx1 = exA[1] - xx;
            const float dy0 = eyA[0] - yy, dy1 = eyA[1] - yy;
            const float adx0 = a * dx0, adx1 = a * dx1;
            const float bdy0 = b2 * dy0, bdy1 = b2 * dy1;
            const float cdy0 = c * dy0 * dy0, cdy1 = c * dy1 * dy1;
            const float ax0 = a * VxA[0], ax1 = a * VxA[1];
            const float cy0 = c * VyA[0], cy1 = c * VyA[1];
            #pragma unroll
            for (int py = 0; py < 2; ++py) {
                const float bdyp = py ? bdy1 : bdy0;
                const float cdyp = py ? cdy1 : cdy0;
                const float cyp  = py ? cy1 : cy0;
                #pragma unroll
                for (int px = 0; px < 2; ++px) {
                    const float dxp  = px ? dx1 : dx0;
                    const float adxp = px ? adx1 : adx0;
                    const float axp  = px ? ax1 : ax0;
                    float q = dxp * (adxp + bdyp) + cdyp;
                    float bil = -((q + axp) + cyp);
                    bil = fminf(fmaxf(bil, -20.0f), 0.0f);
                    bil = inside ? bil : -1e9f;   // exp flushes to +0
                    float w = op * __expf(bil);
                    if (py == 0 && px == 0) { S00 += w; mn00 = fminf(mn00, w); mx00 = fmaxf(mx00, w); }
                    if (py == 0 && px == 1) { S01 += w; mn01 = fminf(mn01, w); mx01 = fmaxf(mx01, w); }
                    if (py == 1 && px == 0) { S10 += w; mn10 = fminf(mn10, w); mx10 = fmaxf(mx10, w); }
                    if (py == 1 && px == 1) { S11 += w; mn11 = fminf(mn11, w); mx11 = fmaxf(mx11, w); }
                }
            }
        }
    }
    if (wave > 0) {
        pS[wave - 1][lane]  = make_float4(S00, S01, S10, S11);
        pMn[wave - 1][lane] = make_float4(mn00, mn01, mn10, mn11);
        pMx[wave - 1][lane] = make_float4(mx00, mx01, mx10, mx11);
    }
    __syncthreads();
    if (wave == 0) {
        #pragma unroll
        for (int k = 0; k < 7; ++k) {
            float4 s = pS[k][lane], m = pMn[k][lane], M = pMx[k][lane];
            S00 += s.x; S01 += s.y; S10 += s.z; S11 += s.w;
            mn00 = fminf(mn00, m.x); mn01 = fminf(mn01, m.y);
            mn10 = fminf(mn10, m.z); mn11 = fminf(mn11, m.w);
            mx00 = fmaxf(mx00, M.x); mx01 = fmaxf(mx01, M.y);
            mx10 = fmaxf(mx10, M.z); mx11 = fmaxf(mx11, M.w);
        }
        if (len < 512) {
            mn00 = fminf(mn00, 0.f); mn01 = fminf(mn01, 0.f);
            mn10 = fminf(mn10, 0.f); mn11 = fminf(mn11, 0.f);
            mx00 = fmaxf(mx00, 0.f); mx01 = fmaxf(mx01, 0.f);
            mx10 = fmaxf(mx10, 0.f); mx11 = fmaxf(mx11, 0.f);
        }
        float S4[4]  = {S00, S01, S10, S11};
        float mn4[4] = {mn00, mn01, mn10, mn11};
        float mx4[4] = {mx00, mx01, mx10, mx11};
        #pragma unroll
        for (int pp = 0; pp < 4; ++pp) {
            float S = S4[pp];
            float dmv = 0.5f * (S - 512.0f * mn4[pp]) / (mx4[pp] - mn4[pp] + 1e-6f)
                      + S / (S + 1e-6f);
            const int py = pp >> 1, px = pp & 1;
            dm[(v * 224 + ty0 + 2 * qy + py) * 224 + tx0 + 2 * qx + px] = dmv;
        }
    }
}

// Fused: d1 = where(d, blur(d)); d2 = where(d1, blur(d1));
// per-block partial (sum, sumsq) -> partials -> LLC barrier -> every block
// reduces 588 partials (double) and writes out = (d2-mean)/(sd+eps) from
// registers. Tile 16x16 + halo 6; blur work is UNIFORM so the barrier costs
// only sync latency. dm read with plain loads (kernel boundary = coherence).
__global__ __launch_bounds__(256, 3) void blur_norm_kernel(
    const float* __restrict__ in, float* __restrict__ out,
    float2* __restrict__ partials, unsigned* __restrict__ cnts) {
    __shared__ float A[28 * 29];
    __shared__ float T[28 * 29];
    __shared__ float r1[4], r2[4];
    __shared__ double s1[256], s2[256];
    const int v = blockIdx.z;
    const int tx0 = blockIdx.x * 16, ty0 = blockIdx.y * 16;
    const int tid = threadIdx.x;
    const int lane = tid & 63, wave = tid >> 6;
    const float kw[7] = {0.00443305f, 0.05400558f, 0.24203623f, 0.39905030f,
                         0.24203623f, 0.05400558f, 0.00443305f};
    const float* __restrict__ chan = in + v * 224 * 224;

    for (int idx = tid; idx < 28 * 28; idx += 256) {
        int rr = idx / 28, c = idx % 28;
        int gyy = ty0 - 6 + rr, gxx = tx0 - 6 + c;
        float val = 0.0f;
        if (gyy >= 0 && gyy < 224 && gxx >= 0 && gxx < 224) val = chan[gyy * 224 + gxx];
        A[rr * 29 + c] = val;
    }
    __syncthreads();
    for (int idx = tid; idx < 22 * 28; idx += 256) {
        int rr = 3 + idx / 28, c = idx % 28;
        float s = 0.0f;
        #pragma unroll
        for (int i = 0; i < 7; ++i) s += kw[i] * A[(rr - 3 + i) * 29 + c];
        T[rr * 29 + c] = s;
    }
    __syncthreads();
    for (int idx = tid; idx < 22 * 22; idx += 256) {
        int rr = 3 + idx / 22, c = 3 + idx % 22;
        int gyy = ty0 - 6 + rr, gxx = tx0 - 6 + c;
        float s = 0.0f;
        #pragma unroll
        for (int j = 0; j < 7; ++j) s += kw[j] * T[rr * 29 + c - 3 + j];
        float ctr = A[rr * 29 + c];
        float d1 = ctr > 1e-6f ? ctr : s;
        if (gyy < 0 || gyy > 223 || gxx < 0 || gxx > 223) d1 = 0.0f;
        A[rr * 29 + c] = d1;
    }
    __syncthreads();
    for (int idx = tid; idx < 16 * 22; idx += 256) {
        int rr = 6 + idx / 22, c = 3 + idx % 22;
        float s = 0.0f;
        #pragma unroll
        for (int i = 0; i < 7; ++i) s += kw[i] * A[(rr - 3 + i) * 29 + c];
        T[rr * 29 + c] = s;
    }
    __syncthreads();
    // one output px per thread; KEEP d2 in a register across the barrier
    const int rr2 = 6 + (tid >> 4), cc2 = 6 + (tid & 15);
    float d2;
    {
        float s = 0.0f;
        #pragma unroll
        for (int j = 0; j < 7; ++j) s += kw[j] * T[rr2 * 29 + cc2 - 3 + j];
        float ctr = A[rr2 * 29 + cc2];
        d2 = ctr > 1e-6f ? ctr : s;
    }
    float ls1 = d2, ls2 = d2 * d2;
    #pragma unroll
    for (int o = 32; o >= 1; o >>= 1) {
        ls1 += __shfl_xor(ls1, o);
        ls2 += __shfl_xor(ls2, o);
    }
    if (lane == 0) { r1[wave] = ls1; r2[wave] = ls2; }
    __syncthreads();
    if (tid == 0) {
        float a = r1[0] + r1[1] + r1[2] + r1[3];
        float b = r2[0] + r2[1] + r2[2] + r2[3];
        float* pb = (float*)&partials[(v * 14 + blockIdx.y) * 14 + blockIdx.x];
        g_st(pb + 0, a);
        g_st(pb + 1, b);
    }

    grid_barrier(&cnts[0]);  // all partials visible at LLC

    // global stats from 588 partials (double), then normalize from registers
    double a = 0.0, b = 0.0;
    const float* pb = (const float*)partials;
    for (int i = tid; i < 588; i += 256) {
        a += (double)g_ld(pb + 2 * i);
        b += (double)g_ld(pb + 2 * i + 1);
    }
    s1[tid] = a; s2[tid] = b;
    __syncthreads();
    for (int s = 128; s >= 1; s >>= 1) {
        if (tid < s) { s1[tid] += s1[tid + s]; s2[tid] += s2[tid + s]; }
        __syncthreads();
    }
    const double M = 150528.0;
    double mean = s1[0] / M;
    double var = (s2[0] - M * mean * mean) / (M - 1.0);
    double sd = sqrt(var > 0.0 ? var : 0.0);
    const float fmean = (float)mean;
    const float finv = 1.0f / ((float)sd + 1e-6f);
    out[(v * 224 + ty0 + (tid >> 4)) * 224 + tx0 + (tid & 15)] =
        (d2 - fmean) * finv;
}

extern "C" void kernel_launch(void* const* d_in, const int* in_sizes, int n_in,
                              void* d_out, int out_size, void* d_ws, size_t ws_size,
                              hipStream_t stream) {
    const float* position   = (const float*)d_in[0];  // (1,512,3)
    const float* cov3d      = (const float*)d_in[1];  // (1,512,3,3)
    const float* opacity    = (const float*)d_in[2];  // (1,512)
    const float* importance = (const float*)d_in[3];  // (1,1000)
    float* out = (float*)d_out;                       // (1,3,224,224)

    float* dmA       = (float*)d_ws;                          // 150528 floats
    float2* partials = (float2*)((float*)d_ws + 150528);      // 588 float2
    unsigned* cnts   = (unsigned*)((float*)d_ws + 150528 + 1176);  // 1 u32

    hipLaunchKernelGGL(splat_fused_kernel, dim3(14, 14, 3), dim3(512), 0, stream,
                       position, cov3d, opacity, importance, dmA, cnts);
    hipLaunchKernelGGL(blur_norm_kernel, dim3(14, 14, 3), dim3(256), 0, stream,
                       dmA, out, partials, cnts);
}

// Round 4
// 90.251 us; speedup vs baseline: 2.2207x; 1.1804x over previous
//
#include <hip/hip_runtime.h>
#include <math.h>

// ---------------------------------------------------------------------------
// FullGaussianProjector: B=1, N=512, 3 views, 224x224 out, half-res 112x112.
// R9: R8 structure (2 dispatches) + CHEAP grid barrier.
//   R8 post-mortem: single-counter barrier = 588 same-cacheline atomicAdds,
//   serialized in the TCC (~25ns each) ~= 15-16us — more than the normalize
//   dispatch it replaced. Fix:
//     - arrival spread over 32 counters on distinct 128B cachelines
//       (parallel across TCC channels, ~18 RMWs each)
//     - one poller block sums the 32 counters and sets a release flag
//     - all other blocks spin READ-ONLY on the flag (no RMW contention)
//   All barrier traffic stays relaxed agent-scope (LLC-coherent, no cache
//   maintenance). Kernel 1 clears the counters (kernel boundary orders it).
//   kernel 1 (splat, 512 thr): R0-proven per-tile cull/compact + quad eval,
//     no barrier -> hardware dynamically rebalances non-uniform tiles.
//   kernel 2 (blur2 + stats + normalize, 256 thr): blur uniform per block;
//     d2 stays in registers across the barrier; out written exactly once.
// NOTE (R5 lesson): a,2b,c,op must stay f32 — bf16 on the exponent path
// fails absmax through the (wmax-wmin) normalization.
// ---------------------------------------------------------------------------

#define NBLOCKS 588u
#define NARR 32          // arrival counters, one per 128B cacheline
#define FLAG_IDX (NARR * 32)   // release flag, its own cacheline

__device__ __forceinline__ float g_ld(const float* p) {
    return __hip_atomic_load(p, __ATOMIC_RELAXED, __HIP_MEMORY_SCOPE_AGENT);
}
__device__ __forceinline__ void g_st(float* p, float v) {
    __hip_atomic_store(p, v, __ATOMIC_RELAXED, __HIP_MEMORY_SCOPE_AGENT);
}

// Cheap grid barrier: spread arrival + single poller + broadcast release.
// No cache maintenance; cross-block data must use agent-scope atomics.
__device__ __forceinline__ void grid_barrier(unsigned* cnts, int arrIdx, bool poller) {
    __syncthreads();
    if (threadIdx.x == 0) {
        asm volatile("s_waitcnt vmcnt(0)" ::: "memory");  // partials acked at LLC
        __hip_atomic_fetch_add(&cnts[arrIdx * 32], 1u,
                               __ATOMIC_RELAXED, __HIP_MEMORY_SCOPE_AGENT);
        unsigned* flagp = &cnts[FLAG_IDX];
        if (poller) {
            for (;;) {
                unsigned s = 0;
                #pragma unroll
                for (int i = 0; i < NARR; ++i)
                    s += __hip_atomic_load(&cnts[i * 32],
                                           __ATOMIC_RELAXED, __HIP_MEMORY_SCOPE_AGENT);
                if (s == NBLOCKS) break;
                __builtin_amdgcn_s_sleep(2);
            }
            asm volatile("" ::: "memory");  // flag store after poll loads
            __hip_atomic_store(flagp, 1u, __ATOMIC_RELAXED, __HIP_MEMORY_SCOPE_AGENT);
        } else {
            while (__hip_atomic_load(flagp, __ATOMIC_RELAXED,
                                     __HIP_MEMORY_SCOPE_AGENT) == 0u)
                __builtin_amdgcn_s_sleep(2);
        }
    }
    __syncthreads();
}

__device__ __forceinline__ float wave_min(float v) {
    #pragma unroll
    for (int o = 32; o >= 1; o >>= 1) v = fminf(v, __shfl_xor(v, o));
    return v;
}

// Block: 512 threads (8 waves), tile 16x16 full-res px (8x8 quads), grid (14,14,3).
__global__ __launch_bounds__(512) void splat_fused_kernel(
    const float* __restrict__ position, const float* __restrict__ cov3d,
    const float* __restrict__ opacity, const float* __restrict__ importance,
    float* __restrict__ dm, unsigned* __restrict__ cnts) {
    __shared__ float4 lsA[512];        // a, 2b, c, op
    __shared__ float2 lsB[512];        // gx, gy
    __shared__ float red[8 * 6];       // cross-wave min/max scratch
    __shared__ float4 pS[7][64], pMn[7][64], pMx[7][64];
    __shared__ int cnt;
    const int v = blockIdx.z;
    const int tx0 = blockIdx.x * 16, ty0 = blockIdx.y * 16;
    const int tid = threadIdx.x;
    const int lane = tid & 63, wave = tid >> 6;

    // clear kernel-2 barrier counters + flag (ws is poisoned each iteration;
    // the kernel boundary flush makes this visible before kernel 2 starts)
    if (blockIdx.x == 0 && blockIdx.y == 0 && blockIdx.z == 0) {
        for (int i = tid; i <= FLAG_IDX; i += 512) cnts[i] = 0;
    }

    // ---------------- setup (1 gaussian per thread) ----------------
    const int n = tid;
    const float p0 = position[n * 3 + 0];
    const float p1 = position[n * 3 + 1];
    const float p2 = position[n * 3 + 2];
    const float opimp = opacity[n] * fminf(fmaxf(importance[n], 0.5f), 2.0f);

    {
        float vals[6] = {p0, -p0, p1, -p1, p2, -p2};
        #pragma unroll
        for (int k = 0; k < 6; ++k) {
            float r = wave_min(vals[k]);
            if (lane == 0) red[wave * 6 + k] = r;
        }
    }
    __syncthreads();
    float mn6[6];
    #pragma unroll
    for (int k = 0; k < 6; ++k) {
        float r = red[k];
        #pragma unroll
        for (int w = 1; w < 8; ++w) r = fminf(r, red[w * 6 + k]);
        mn6[k] = r;
    }
    const float pmn[3] = {mn6[0], mn6[2], mn6[4]};
    const float pmx[3] = {-mn6[1], -mn6[3], -mn6[5]};

    float c00 = cov3d[n * 9 + 0], c01 = cov3d[n * 9 + 1], c02 = cov3d[n * 9 + 2];
    float c10 = cov3d[n * 9 + 3], c11 = cov3d[n * 9 + 4], c12 = cov3d[n * 9 + 5];
    float c20 = cov3d[n * 9 + 6], c21 = cov3d[n * 9 + 7], c22 = cov3d[n * 9 + 8];
    for (int vv = 0; vv <= v; ++vv) {
        float s01 = 0.5f * (c01 + c10);
        float s02 = 0.5f * (c02 + c20);
        float s12 = 0.5f * (c12 + c21);
        float s00 = c00 + 1e-6f;
        float s11 = c11 + 1e-6f;
        float s22 = c22 + 1e-6f;
        float nrm = sqrtf(s00 * s00 + s11 * s11 + s22 * s22 +
                          2.0f * (s01 * s01 + s02 * s02 + s12 * s12));
        float inv = 1.0f / (nrm + 1e-6f);
        c00 = s00 * inv; c11 = s11 * inv; c22 = s22 * inv;
        c01 = s01 * inv; c10 = c01; c02 = s02 * inv; c20 = c02;
        c12 = s12 * inv; c21 = c12;
    }
    float cof00 = c11 * c22 - c12 * c12;
    float cof01 = c02 * c12 - c01 * c22;
    float cof02 = c01 * c12 - c02 * c11;
    float det = c00 * cof00 + c01 * cof01 + c02 * cof02;
    float idet = 1.0f / det;
    float i00 = cof00 * idet;
    float i01 = cof01 * idet;
    float i02 = cof02 * idet;
    float i11 = (c00 * c22 - c02 * c02) * idet;
    float i12 = (c02 * c01 - c00 * c12) * idet;
    float i22 = (c00 * c11 - c01 * c01) * idet;

    float Aa, Ab, Ac, prx, pry;
    int ix, iy;
    if (v == 0)      { Aa = i00; Ab = i01; Ac = i11; prx = p0; pry = p1; ix = 0; iy = 1; }
    else if (v == 1) { Aa = i00; Ab = i02; Ac = i22; prx = p0; pry = p2; ix = 0; iy = 2; }
    else             { Aa = i22; Ab = i12; Ac = i11; prx = p2; pry = p1; ix = 2; iy = 1; }
    Aa += 1e-10f;
    Ac += 1e-10f;

    float mnx = pmn[ix], mxx = pmx[ix], mny = pmn[iy], mxy = pmx[iy];
    float rngx = mxx - mnx + 1e-6f;
    float mnx2 = mnx - 0.5f * rngx;
    float mxx2 = mxx + 0.5f * rngx;
    rngx = mxx2 - mnx2 + 1e-6f;
    float rngy = mxy - mny + 1e-6f;
    float mny2 = mny - 0.5f * rngy;
    float mxy2 = mxy + 0.5f * rngy;
    rngy = mxy2 - mny2 + 1e-6f;
    float gx = fminf(fmaxf((prx - mnx2) / rngx * 111.0f, 0.0f), 111.0f);
    float gy = fminf(fmaxf((pry - mny2) / rngy * 111.0f, 0.0f), 111.0f);

    // ---------------- cull + compact into LDS (SoA f32) ----------------
    if (tid == 0) cnt = 0;
    __syncthreads();
    {
        const float bx0 = (float)(tx0 >> 1), bx1 = (float)((tx0 + 15) >> 1);
        const float by0 = (float)(ty0 >> 1), by1 = (float)((ty0 + 15) >> 1);
        float dx = fmaxf(fmaxf(bx0 - gx, gx - bx1), 0.0f);
        float dy = fmaxf(fmaxf(by0 - gy, gy - by1), 0.0f);
        bool pass = (dx * dx + dy * dy) < 400.01f;  // conservative superset
        unsigned long long m = __ballot(pass);
        int base = 0;
        if (lane == 0) base = atomicAdd(&cnt, __popcll(m));
        base = __shfl(base, 0);
        if (pass) {
            int slot = base + __popcll(m & ((1ull << lane) - 1ull));
            lsA[slot] = make_float4(Aa, 2.0f * Ab, Ac, opimp);
            lsB[slot] = make_float2(gx, gy);
        }
    }
    __syncthreads();
    const int len = cnt;

    // quad owned by this lane: half-res pixel (xh, yh)
    const int qx = lane & 7, qy = lane >> 3;
    const int xh = (tx0 >> 1) + qx;
    const int yh = (ty0 >> 1) + qy;

    if (len == 0) {  // uniform branch: whole block exits
        if (wave == 0) {
            #pragma unroll
            for (int py = 0; py < 2; ++py)
                #pragma unroll
                for (int px = 0; px < 2; ++px)
                    dm[(v * 224 + ty0 + 2 * qy + py) * 224 + tx0 + 2 * qx + px] = 0.0f;
        }
        return;
    }

    const int npad = (len + 15) & ~15;
    if (tid < npad - len) {  // no-op pad gaussians (mask always fails -> w=0)
        lsA[len + tid] = make_float4(1.0f, 0.0f, 1.0f, 0.0f);
        lsB[len + tid] = make_float2(1e9f, 1e9f);
    }
    __syncthreads();

    // per-parity constants (generic formula, preserves edge clamping exactly)
    float exA[2], eyA[2], VxA[2], VyA[2];
    #pragma unroll
    for (int p = 0; p < 2; ++p) {
        int xlo = xh - 1 + p; int xhi = min(xlo + 1, 111); xlo = max(xlo, 0);
        float wlo = p ? 0.75f : 0.25f, whi = 1.0f - wlo;
        exA[p] = wlo * (float)xlo + whi * (float)xhi;
        VxA[p] = wlo * whi * (float)(xhi - xlo) * (float)(xhi - xlo);
        int ylo = yh - 1 + p; int yhi2 = min(ylo + 1, 111); ylo = max(ylo, 0);
        eyA[p] = wlo * (float)ylo + whi * (float)yhi2;
        VyA[p] = wlo * whi * (float)(yhi2 - ylo) * (float)(yhi2 - ylo);
    }
    const float fxh = (float)xh, fyh = (float)yh;

    // ---------------- list chunk for this wave, quad eval ----------------
    const int chunk = npad >> 3;           // multiple of 2
    const int cbeg = wave * chunk, cend = cbeg + chunk;

    float S00 = 0.f, S01 = 0.f, S10 = 0.f, S11 = 0.f;
    float mn00 = INFINITY, mn01 = INFINITY, mn10 = INFINITY, mn11 = INFINITY;
    float mx00 = -INFINITY, mx01 = -INFINITY, mx10 = -INFINITY, mx11 = -INFINITY;

    for (int i = cbeg; i < cend; i += 2) {
        float4 gA0 = lsA[i], gA1 = lsA[i + 1];
        float2 gB0 = lsB[i], gB1 = lsB[i + 1];
        #pragma unroll
        for (int u = 0; u < 2; ++u) {
            const float4 gA = u ? gA1 : gA0;
            const float2 gB = u ? gB1 : gB0;
            const float a = gA.x, b2 = gA.y, c = gA.z, op = gA.w;
            const float xx = gB.x, yy = gB.y;
            const float dxh = fxh - xx, dyh = fyh - yy;
            const bool inside = dxh * dxh + dyh * dyh < 400.0f;
            const float dx0 = exA[0] - xx, dx1 = exA[1] - xx;
            const float dy0 = eyA[0] - yy, dy1 = eyA[1] - yy;
            const float adx0 = a * dx0, adx1 = a * dx1;
            const float bdy0 = b2 * dy0, bdy1 = b2 * dy1;
            const float cdy0 = c * dy0 * dy0, cdy1 = c * dy1 * dy1;
            const float ax0 = a * VxA[0], ax1 = a * VxA[1];
            const float cy0 = c * VyA[0], cy1 = c * VyA[1];
            #pragma unroll
            for (int py = 0; py < 2; ++py) {
                const float bdyp = py ? bdy1 : bdy0;
                const float cdyp = py ? cdy1 : cdy0;
                const float cyp  = py ? cy1 : cy0;
                #pragma unroll
                for (int px = 0; px < 2; ++px) {
                    const float dxp  = px ? dx1 : dx0;
                    const float adxp = px ? adx1 : adx0;
                    const float axp  = px ? ax1 : ax0;
                    float q = dxp * (adxp + bdyp) + cdyp;
                    float bil = -((q + axp) + cyp);
                    bil = fminf(fmaxf(bil, -20.0f), 0.0f);
                    bil = inside ? bil : -1e9f;   // exp flushes to +0
                    float w = op * __expf(bil);
                    if (py == 0 && px == 0) { S00 += w; mn00 = fminf(mn00, w); mx00 = fmaxf(mx00, w); }
                    if (py == 0 && px == 1) { S01 += w; mn01 = fminf(mn01, w); mx01 = fmaxf(mx01, w); }
                    if (py == 1 && px == 0) { S10 += w; mn10 = fminf(mn10, w); mx10 = fmaxf(mx10, w); }
                    if (py == 1 && px == 1) { S11 += w; mn11 = fminf(mn11, w); mx11 = fmaxf(mx11, w); }
                }
            }
        }
    }
    if (wave > 0) {
        pS[wave - 1][lane]  = make_float4(S00, S01, S10, S11);
        pMn[wave - 1][lane] = make_float4(mn00, mn01, mn10, mn11);
        pMx[wave - 1][lane] = make_float4(mx00, mx01, mx10, mx11);
    }
    __syncthreads();
    if (wave == 0) {
        #pragma unroll
        for (int k = 0; k < 7; ++k) {
            float4 s = pS[k][lane], m = pMn[k][lane], M = pMx[k][lane];
            S00 += s.x; S01 += s.y; S10 += s.z; S11 += s.w;
            mn00 = fminf(mn00, m.x); mn01 = fminf(mn01, m.y);
            mn10 = fminf(mn10, m.z); mn11 = fminf(mn11, m.w);
            mx00 = fmaxf(mx00, M.x); mx01 = fmaxf(mx01, M.y);
            mx10 = fmaxf(mx10, M.z); mx11 = fmaxf(mx11, M.w);
        }
        if (len < 512) {
            mn00 = fminf(mn00, 0.f); mn01 = fminf(mn01, 0.f);
            mn10 = fminf(mn10, 0.f); mn11 = fminf(mn11, 0.f);
            mx00 = fmaxf(mx00, 0.f); mx01 = fmaxf(mx01, 0.f);
            mx11 = fmaxf(mx11, 0.f); mx10 = fmaxf(mx10, 0.f);
        }
        float S4[4]  = {S00, S01, S10, S11};
        float mn4[4] = {mn00, mn01, mn10, mn11};
        float mx4[4] = {mx00, mx01, mx10, mx11};
        #pragma unroll
        for (int pp = 0; pp < 4; ++pp) {
            float S = S4[pp];
            float dmv = 0.5f * (S - 512.0f * mn4[pp]) / (mx4[pp] - mn4[pp] + 1e-6f)
                      + S / (S + 1e-6f);
            const int py = pp >> 1, px = pp & 1;
            dm[(v * 224 + ty0 + 2 * qy + py) * 224 + tx0 + 2 * qx + px] = dmv;
        }
    }
}

// Fused: d1 = where(d, blur(d)); d2 = where(d1, blur(d1));
// per-block partial (sum, sumsq) -> partials -> cheap LLC barrier -> every
// block reduces 588 partials (double) and writes out = (d2-mean)/(sd+eps)
// from registers. Tile 16x16 + halo 6; blur work is UNIFORM so the barrier
// costs only sync latency. dm read with plain loads (kernel boundary flush).
__global__ __launch_bounds__(256, 3) void blur_norm_kernel(
    const float* __restrict__ in, float* __restrict__ out,
    float2* __restrict__ partials, unsigned* __restrict__ cnts) {
    __shared__ float A[28 * 29];
    __shared__ float T[28 * 29];
    __shared__ float r1[4], r2[4];
    __shared__ double s1[256], s2[256];
    const int v = blockIdx.z;
    const int tx0 = blockIdx.x * 16, ty0 = blockIdx.y * 16;
    const int tid = threadIdx.x;
    const int lane = tid & 63, wave = tid >> 6;
    const int bid = (v * 14 + blockIdx.y) * 14 + blockIdx.x;
    const float kw[7] = {0.00443305f, 0.05400558f, 0.24203623f, 0.39905030f,
                         0.24203623f, 0.05400558f, 0.00443305f};
    const float* __restrict__ chan = in + v * 224 * 224;

    for (int idx = tid; idx < 28 * 28; idx += 256) {
        int rr = idx / 28, c = idx % 28;
        int gyy = ty0 - 6 + rr, gxx = tx0 - 6 + c;
        float val = 0.0f;
        if (gyy >= 0 && gyy < 224 && gxx >= 0 && gxx < 224) val = chan[gyy * 224 + gxx];
        A[rr * 29 + c] = val;
    }
    __syncthreads();
    for (int idx = tid; idx < 22 * 28; idx += 256) {
        int rr = 3 + idx / 28, c = idx % 28;
        float s = 0.0f;
        #pragma unroll
        for (int i = 0; i < 7; ++i) s += kw[i] * A[(rr - 3 + i) * 29 + c];
        T[rr * 29 + c] = s;
    }
    __syncthreads();
    for (int idx = tid; idx < 22 * 22; idx += 256) {
        int rr = 3 + idx / 22, c = 3 + idx % 22;
        int gyy = ty0 - 6 + rr, gxx = tx0 - 6 + c;
        float s = 0.0f;
        #pragma unroll
        for (int j = 0; j < 7; ++j) s += kw[j] * T[rr * 29 + c - 3 + j];
        float ctr = A[rr * 29 + c];
        float d1 = ctr > 1e-6f ? ctr : s;
        if (gyy < 0 || gyy > 223 || gxx < 0 || gxx > 223) d1 = 0.0f;
        A[rr * 29 + c] = d1;
    }
    __syncthreads();
    for (int idx = tid; idx < 16 * 22; idx += 256) {
        int rr = 6 + idx / 22, c = 3 + idx % 22;
        float s = 0.0f;
        #pragma unroll
        for (int i = 0; i < 7; ++i) s += kw[i] * A[(rr - 3 + i) * 29 + c];
        T[rr * 29 + c] = s;
    }
    __syncthreads();
    // one output px per thread; KEEP d2 in a register across the barrier
    const int rr2 = 6 + (tid >> 4), cc2 = 6 + (tid & 15);
    float d2;
    {
        float s = 0.0f;
        #pragma unroll
        for (int j = 0; j < 7; ++j) s += kw[j] * T[rr2 * 29 + cc2 - 3 + j];
        float ctr = A[rr2 * 29 + cc2];
        d2 = ctr > 1e-6f ? ctr : s;
    }
    float ls1 = d2, ls2 = d2 * d2;
    #pragma unroll
    for (int o = 32; o >= 1; o >>= 1) {
        ls1 += __shfl_xor(ls1, o);
        ls2 += __shfl_xor(ls2, o);
    }
    if (lane == 0) { r1[wave] = ls1; r2[wave] = ls2; }
    __syncthreads();
    if (tid == 0) {
        float a = r1[0] + r1[1] + r1[2] + r1[3];
        float b = r2[0] + r2[1] + r2[2] + r2[3];
        float* pb = (float*)&partials[bid];
        g_st(pb + 0, a);
        g_st(pb + 1, b);
    }

    grid_barrier(cnts, bid & (NARR - 1), bid == 0);  // partials visible at LLC

    // global stats from 588 partials (double), then normalize from registers
    double a = 0.0, b = 0.0;
    const float* pb = (const float*)partials;
    for (int i = tid; i < 588; i += 256) {
        a += (double)g_ld(pb + 2 * i);
        b += (double)g_ld(pb + 2 * i + 1);
    }
    s1[tid] = a; s2[tid] = b;
    __syncthreads();
    for (int s = 128; s >= 1; s >>= 1) {
        if (tid < s) { s1[tid] += s1[tid + s]; s2[tid] += s2[tid + s]; }
        __syncthreads();
    }
    const double M = 150528.0;
    double mean = s1[0] / M;
    double var = (s2[0] - M * mean * mean) / (M - 1.0);
    double sd = sqrt(var > 0.0 ? var : 0.0);
    const float fmean = (float)mean;
    const float finv = 1.0f / ((float)sd + 1e-6f);
    out[(v * 224 + ty0 + (tid >> 4)) * 224 + tx0 + (tid & 15)] =
        (d2 - fmean) * finv;
}

extern "C" void kernel_launch(void* const* d_in, const int* in_sizes, int n_in,
                              void* d_out, int out_size, void* d_ws, size_t ws_size,
                              hipStream_t stream) {
    const float* position   = (const float*)d_in[0];  // (1,512,3)
    const float* cov3d      = (const float*)d_in[1];  // (1,512,3,3)
    const float* opacity    = (const float*)d_in[2];  // (1,512)
    const float* importance = (const float*)d_in[3];  // (1,1000)
    float* out = (float*)d_out;                       // (1,3,224,224)

    float* dmA       = (float*)d_ws;                          // 150528 floats
    float2* partials = (float2*)((float*)d_ws + 150528);      // 588 float2
    unsigned* cnts   = (unsigned*)((float*)d_ws + 150528 + 1176);  // 1025 u32

    hipLaunchKernelGGL(splat_fused_kernel, dim3(14, 14, 3), dim3(512), 0, stream,
                       position, cov3d, opacity, importance, dmA, cnts);
    hipLaunchKernelGGL(blur_norm_kernel, dim3(14, 14, 3), dim3(256), 0, stream,
                       dmA, out, partials, cnts);
}